// Round 1
// baseline (6656.834 us; speedup 1.0000x reference)
//
#include <hip/hip_runtime.h>
#include <math.h>

#define IN_USER 256
#define IN_ITEM 128
#define HID 128
#define OUTF 64

__device__ __forceinline__ void atomAddF(float* p, float v) {
#if defined(__HIP_PLATFORM_AMD__)
    unsafeAtomicAdd(p, v);   // global_atomic_add_f32 (HW fp atomic)
#else
    atomicAdd(p, v);
#endif
}

// ---------------- degree histogram ----------------
__global__ __launch_bounds__(256) void deg_kernel(
        const int* __restrict__ src, const int* __restrict__ dst,
        int* __restrict__ degs, int* __restrict__ degd, int E) {
    const int stride = gridDim.x * blockDim.x;
    for (int i = blockIdx.x * blockDim.x + threadIdx.x; i < E; i += stride) {
        atomicAdd(&degs[src[i]], 1);
        atomicAdd(&degd[dst[i]], 1);
    }
}

__global__ __launch_bounds__(256) void inv_kernel(
        const int* __restrict__ deg, float* __restrict__ inv, int n) {
    const int stride = gridDim.x * blockDim.x;
    for (int i = blockIdx.x * blockDim.x + threadIdx.x; i < n; i += stride) {
        const int d = deg[i];
        inv[i] = 1.0f / sqrtf((float)(d > 1 ? d : 1));
    }
}

// ------------- T = (X @ W) * invout[:,None] -------------
// 64x64 output tile per 256-thread block, BK=16, 4x4 per thread, fp32.
template<int K, int N>
__global__ __launch_bounds__(256) void gemm_scale(
        const float* __restrict__ X, const float* __restrict__ W,
        const float* __restrict__ invout, float* __restrict__ T, int M) {
    __shared__ float xs[16][64];   // xs[k][m] = X[row0+m][kk+k]
    __shared__ float ws[16][64];   // ws[k][n] = W[kk+k][col0+n]
    const int row0 = blockIdx.x * 64;
    const int col0 = blockIdx.y * 64;
    const int tid = threadIdx.x;
    const int tm = (tid >> 4) * 4;
    const int tn = (tid & 15) * 4;
    const int xr = tid >> 2;           // 0..63 row in tile
    const int xc = (tid & 3) * 4;      // 0,4,8,12 col chunk
    const int wk = tid >> 4;           // 0..15
    const int wc = (tid & 15) * 4;     // 0..60
    float acc[4][4] = {};
    for (int kk = 0; kk < K; kk += 16) {
        float4 xv = make_float4(0.f, 0.f, 0.f, 0.f);
        const int xrow = row0 + xr;
        if (xrow < M)
            xv = *reinterpret_cast<const float4*>(X + (size_t)xrow * K + kk + xc);
        const float4 wv = *reinterpret_cast<const float4*>(
            W + (size_t)(kk + wk) * N + col0 + wc);
        __syncthreads();               // previous iter's LDS reads done
        xs[xc + 0][xr] = xv.x; xs[xc + 1][xr] = xv.y;
        xs[xc + 2][xr] = xv.z; xs[xc + 3][xr] = xv.w;
        ws[wk][wc + 0] = wv.x; ws[wk][wc + 1] = wv.y;
        ws[wk][wc + 2] = wv.z; ws[wk][wc + 3] = wv.w;
        __syncthreads();
#pragma unroll
        for (int k = 0; k < 16; ++k) {
            const float4 a = *reinterpret_cast<const float4*>(&xs[k][tm]);
            const float4 b = *reinterpret_cast<const float4*>(&ws[k][tn]);
            acc[0][0] += a.x * b.x; acc[0][1] += a.x * b.y;
            acc[0][2] += a.x * b.z; acc[0][3] += a.x * b.w;
            acc[1][0] += a.y * b.x; acc[1][1] += a.y * b.y;
            acc[1][2] += a.y * b.z; acc[1][3] += a.y * b.w;
            acc[2][0] += a.z * b.x; acc[2][1] += a.z * b.y;
            acc[2][2] += a.z * b.z; acc[2][3] += a.z * b.w;
            acc[3][0] += a.w * b.x; acc[3][1] += a.w * b.y;
            acc[3][2] += a.w * b.z; acc[3][3] += a.w * b.w;
        }
    }
#pragma unroll
    for (int i = 0; i < 4; ++i) {
        const int row = row0 + tm + i;
        if (row < M) {
            const float s = invout[row];
            float4 o;
            o.x = acc[i][0] * s; o.y = acc[i][1] * s;
            o.z = acc[i][2] * s; o.w = acc[i][3] * s;
            *reinterpret_cast<float4*>(T + (size_t)row * N + col0 + tn) = o;
        }
    }
}

// ------------- agg[dst] += T[src] * invin[dst] over edges -------------
template<int F>
__global__ __launch_bounds__(256) void scatter_add(
        const float* __restrict__ T, const int* __restrict__ src,
        const int* __restrict__ dst, const float* __restrict__ invin,
        float* __restrict__ agg, int E) {
    constexpr int LPE = F / 4;        // lanes per edge (float4 each)
    constexpr int EPB = 256 / LPE;    // edges per block-iteration
    const int sub = threadIdx.x / LPE;
    const int f4 = (threadIdx.x % LPE) * 4;
    for (int e = blockIdx.x * EPB + sub; e < E; e += gridDim.x * EPB) {
        const int s = src[e];
        const int d = dst[e];
        const float sc = invin[d];
        const float4 v = *reinterpret_cast<const float4*>(T + (size_t)s * F + f4);
        float* p = agg + (size_t)d * F + f4;
        atomAddF(p + 0, v.x * sc);
        atomAddF(p + 1, v.y * sc);
        atomAddF(p + 2, v.z * sc);
        atomAddF(p + 3, v.w * sc);
    }
}

// ------------- buf = act(buf + b0 [+ b1]) -------------
template<int F, bool RELU, bool TWOB>
__global__ __launch_bounds__(256) void bias_act(
        float* __restrict__ buf, const float* __restrict__ b0,
        const float* __restrict__ b1, int total4) {
    const int stride = gridDim.x * blockDim.x;
    for (int i = blockIdx.x * blockDim.x + threadIdx.x; i < total4; i += stride) {
        const int f4 = (i & (F / 4 - 1)) * 4;
        float4 v = reinterpret_cast<float4*>(buf)[i];
        const float4 a = *reinterpret_cast<const float4*>(b0 + f4);
        v.x += a.x; v.y += a.y; v.z += a.z; v.w += a.w;
        if (TWOB) {
            const float4 c = *reinterpret_cast<const float4*>(b1 + f4);
            v.x += c.x; v.y += c.y; v.z += c.z; v.w += c.w;
        }
        if (RELU) {
            v.x = fmaxf(v.x, 0.f); v.y = fmaxf(v.y, 0.f);
            v.z = fmaxf(v.z, 0.f); v.w = fmaxf(v.w, 0.f);
        }
        reinterpret_cast<float4*>(buf)[i] = v;
    }
}

extern "C" void kernel_launch(void* const* d_in, const int* in_sizes, int n_in,
                              void* d_out, int out_size, void* d_ws, size_t ws_size,
                              hipStream_t stream) {
    const float* feat_user = (const float*)d_in[0];
    const float* feat_item = (const float*)d_in[1];
    const int* rates_src = (const int*)d_in[2];
    const int* rates_dst = (const int*)d_in[3];
    const int* rated_src = (const int*)d_in[4];
    const int* rated_dst = (const int*)d_in[5];
    const int* fol_src   = (const int*)d_in[6];
    const int* fol_dst   = (const int*)d_in[7];
    const float* W1_rates = (const float*)d_in[8];
    const float* b1_rates = (const float*)d_in[9];
    const float* W1_rated = (const float*)d_in[10];
    const float* b1_rated = (const float*)d_in[11];
    const float* W1_fol   = (const float*)d_in[12];
    const float* b1_fol   = (const float*)d_in[13];
    const float* W2_rates = (const float*)d_in[14];
    const float* b2_rates = (const float*)d_in[15];
    const float* W2_rated = (const float*)d_in[16];
    const float* b2_rated = (const float*)d_in[17];
    const float* W2_fol   = (const float*)d_in[18];
    const float* b2_fol   = (const float*)d_in[19];

    const int n_user = in_sizes[0] / IN_USER;   // 100000
    const int n_item = in_sizes[1] / IN_ITEM;   // 100000
    const int E0 = in_sizes[2];                 // rates edges
    const int E1 = in_sizes[4];                 // rated edges
    const int E2 = in_sizes[6];                 // fol edges
    const int nmax = n_user > n_item ? n_user : n_item;

    // ---- workspace layout ----
    const size_t NP = 100352;  // padded node stride (256B-aligned arrays)
    int*   deg  = (int*)d_ws;                        // [6][NP] int
    float* inv  = (float*)((char*)d_ws + 6 * NP * 4);// [6][NP] float
    float* t    = inv + 6 * NP;                      // [nmax][HID]
    float* aggU = t + (size_t)nmax * HID;            // [n_user][HID]
    float* aggI = aggU + (size_t)n_user * HID;       // [n_item][HID]
    // total ~158 MB

    float* o_user = (float*)d_out;
    float* o_item = o_user + (size_t)n_user * OUTF;

    // ---- degrees & normalizers (deg[0]=rates_src/user, [1]=rates_dst/item,
    //      [2]=rated_src/item, [3]=rated_dst/user, [4]=fol_src, [5]=fol_dst) ----
    hipMemsetAsync(deg, 0, 6 * NP * 4, stream);
    deg_kernel<<<1024, 256, 0, stream>>>(rates_src, rates_dst, deg + 0 * NP, deg + 1 * NP, E0);
    deg_kernel<<<1024, 256, 0, stream>>>(rated_src, rated_dst, deg + 2 * NP, deg + 3 * NP, E1);
    deg_kernel<<<1024, 256, 0, stream>>>(fol_src,   fol_dst,   deg + 4 * NP, deg + 5 * NP, E2);
    inv_kernel<<<1024, 256, 0, stream>>>(deg, inv, (int)(6 * NP));

    // ---- layer 1 ----
    hipMemsetAsync(aggU, 0, (size_t)n_user * HID * 4, stream);
    hipMemsetAsync(aggI, 0, (size_t)n_item * HID * 4, stream);

    dim3 gU1((n_user + 63) / 64, HID / 64);
    dim3 gI1((n_item + 63) / 64, HID / 64);

    gemm_scale<IN_USER, HID><<<gU1, 256, 0, stream>>>(feat_user, W1_rates, inv + 0 * NP, t, n_user);
    scatter_add<HID><<<8192, 256, 0, stream>>>(t, rates_src, rates_dst, inv + 1 * NP, aggI, E0);

    gemm_scale<IN_ITEM, HID><<<gI1, 256, 0, stream>>>(feat_item, W1_rated, inv + 2 * NP, t, n_item);
    scatter_add<HID><<<8192, 256, 0, stream>>>(t, rated_src, rated_dst, inv + 3 * NP, aggU, E1);

    gemm_scale<IN_USER, HID><<<gU1, 256, 0, stream>>>(feat_user, W1_fol, inv + 4 * NP, t, n_user);
    scatter_add<HID><<<8192, 256, 0, stream>>>(t, fol_src, fol_dst, inv + 5 * NP, aggU, E2);

    bias_act<HID, true, false><<<2048, 256, 0, stream>>>(aggI, b1_rates, nullptr, n_item * HID / 4);
    bias_act<HID, true, true><<<2048, 256, 0, stream>>>(aggU, b1_rated, b1_fol, n_user * HID / 4);

    // ---- layer 2 (aggregate straight into d_out) ----
    hipMemsetAsync(d_out, 0, (size_t)out_size * 4, stream);

    dim3 gU2((n_user + 63) / 64, OUTF / 64);
    dim3 gI2((n_item + 63) / 64, OUTF / 64);

    gemm_scale<HID, OUTF><<<gU2, 256, 0, stream>>>(aggU, W2_rates, inv + 0 * NP, t, n_user);
    scatter_add<OUTF><<<8192, 256, 0, stream>>>(t, rates_src, rates_dst, inv + 1 * NP, o_item, E0);

    gemm_scale<HID, OUTF><<<gI2, 256, 0, stream>>>(aggI, W2_rated, inv + 2 * NP, t, n_item);
    scatter_add<OUTF><<<8192, 256, 0, stream>>>(t, rated_src, rated_dst, inv + 3 * NP, o_user, E1);

    gemm_scale<HID, OUTF><<<gU2, 256, 0, stream>>>(aggU, W2_fol, inv + 4 * NP, t, n_user);
    scatter_add<OUTF><<<8192, 256, 0, stream>>>(t, fol_src, fol_dst, inv + 5 * NP, o_user, E2);

    bias_act<OUTF, false, false><<<2048, 256, 0, stream>>>(o_item, b2_rates, nullptr, n_item * OUTF / 4);
    bias_act<OUTF, false, true><<<2048, 256, 0, stream>>>(o_user, b2_rated, b2_fol, n_user * OUTF / 4);
}

// Round 2
// 1731.019 us; speedup vs baseline: 3.8456x; 3.8456x over previous
//
#include <hip/hip_runtime.h>
#include <math.h>

#define IN_USER 256
#define IN_ITEM 128
#define HID 128
#define OUTF 64

// ---------------- degree histogram ----------------
__global__ __launch_bounds__(256) void deg_kernel(
        const int* __restrict__ src, const int* __restrict__ dst,
        int* __restrict__ degs, int* __restrict__ degd, int E) {
    const int stride = gridDim.x * blockDim.x;
    for (int i = blockIdx.x * blockDim.x + threadIdx.x; i < E; i += stride) {
        atomicAdd(&degs[src[i]], 1);
        atomicAdd(&degd[dst[i]], 1);
    }
}

__global__ __launch_bounds__(256) void inv_kernel(
        const int* __restrict__ deg, float* __restrict__ inv, int n) {
    const int stride = gridDim.x * blockDim.x;
    for (int i = blockIdx.x * blockDim.x + threadIdx.x; i < n; i += stride) {
        const int d = deg[i];
        inv[i] = 1.0f / sqrtf((float)(d > 1 ? d : 1));
    }
}

// ---------------- exclusive scan (one block, n <= ~1M) ----------------
// cursor[i] = sum_{j<i} deg[j]. Single 1024-thread block.
__global__ __launch_bounds__(1024) void exscan_kernel(
        const int* __restrict__ deg, int* __restrict__ cursor, int n) {
    __shared__ int sums[1024];
    const int t = threadIdx.x;
    const int per = (n + 1023) / 1024;
    const int lo = t * per;
    const int hi = (lo + per) < n ? (lo + per) : n;
    int s = 0;
    for (int i = lo; i < hi; ++i) s += deg[i];
    sums[t] = s;
    __syncthreads();
    for (int off = 1; off < 1024; off <<= 1) {
        const int v = (t >= off) ? sums[t - off] : 0;
        __syncthreads();
        sums[t] += v;
        __syncthreads();
    }
    int pre = (t == 0) ? 0 : sums[t - 1];
    for (int i = lo; i < hi; ++i) { cursor[i] = pre; pre += deg[i]; }
}

// ---------------- CSR fill: csr[pos] = src, pos = cursor[dst]++ ----------------
__global__ __launch_bounds__(256) void csr_fill(
        const int* __restrict__ src, const int* __restrict__ dst,
        int* __restrict__ cursor, int* __restrict__ csr, int E) {
    const int stride = gridDim.x * blockDim.x;
    for (int i = blockIdx.x * blockDim.x + threadIdx.x; i < E; i += stride) {
        const int pos = atomicAdd(&cursor[dst[i]], 1);
        csr[pos] = src[i];
    }
}

// ------------- T = (X @ W) * invout[:,None] -------------
// 64x64 output tile per 256-thread block, BK=16, 4x4 per thread, fp32.
template<int K, int N>
__global__ __launch_bounds__(256) void gemm_scale(
        const float* __restrict__ X, const float* __restrict__ W,
        const float* __restrict__ invout, float* __restrict__ T, int M) {
    __shared__ float xs[16][64];   // xs[k][m] = X[row0+m][kk+k]
    __shared__ float ws[16][64];   // ws[k][n] = W[kk+k][col0+n]
    const int row0 = blockIdx.x * 64;
    const int col0 = blockIdx.y * 64;
    const int tid = threadIdx.x;
    const int tm = (tid >> 4) * 4;
    const int tn = (tid & 15) * 4;
    const int xr = tid >> 2;           // 0..63 row in tile
    const int xc = (tid & 3) * 4;      // 0,4,8,12 col chunk
    const int wk = tid >> 4;           // 0..15
    const int wc = (tid & 15) * 4;     // 0..60
    float acc[4][4] = {};
    for (int kk = 0; kk < K; kk += 16) {
        float4 xv = make_float4(0.f, 0.f, 0.f, 0.f);
        const int xrow = row0 + xr;
        if (xrow < M)
            xv = *reinterpret_cast<const float4*>(X + (size_t)xrow * K + kk + xc);
        const float4 wv = *reinterpret_cast<const float4*>(
            W + (size_t)(kk + wk) * N + col0 + wc);
        __syncthreads();               // previous iter's LDS reads done
        xs[xc + 0][xr] = xv.x; xs[xc + 1][xr] = xv.y;
        xs[xc + 2][xr] = xv.z; xs[xc + 3][xr] = xv.w;
        ws[wk][wc + 0] = wv.x; ws[wk][wc + 1] = wv.y;
        ws[wk][wc + 2] = wv.z; ws[wk][wc + 3] = wv.w;
        __syncthreads();
#pragma unroll
        for (int k = 0; k < 16; ++k) {
            const float4 a = *reinterpret_cast<const float4*>(&xs[k][tm]);
            const float4 b = *reinterpret_cast<const float4*>(&ws[k][tn]);
            acc[0][0] += a.x * b.x; acc[0][1] += a.x * b.y;
            acc[0][2] += a.x * b.z; acc[0][3] += a.x * b.w;
            acc[1][0] += a.y * b.x; acc[1][1] += a.y * b.y;
            acc[1][2] += a.y * b.z; acc[1][3] += a.y * b.w;
            acc[2][0] += a.z * b.x; acc[2][1] += a.z * b.y;
            acc[2][2] += a.z * b.z; acc[2][3] += a.z * b.w;
            acc[3][0] += a.w * b.x; acc[3][1] += a.w * b.y;
            acc[3][2] += a.w * b.z; acc[3][3] += a.w * b.w;
        }
    }
#pragma unroll
    for (int i = 0; i < 4; ++i) {
        const int row = row0 + tm + i;
        if (row < M) {
            const float s = invout[row];
            float4 o;
            o.x = acc[i][0] * s; o.y = acc[i][1] * s;
            o.z = acc[i][2] * s; o.w = acc[i][3] * s;
            *reinterpret_cast<float4*>(T + (size_t)row * N + col0 + tn) = o;
        }
    }
}

// ------------- pull-aggregation: one wave per dst node -------------
// out[v] = (maybe out[v]) + (sum_{e in CSR(v)} T[csr[e]]) * invin[v] + bias
// (+ReLU). CSR range = [cursor[v]-deg[v], cursor[v]) after csr_fill.
template<int F, bool ACC, bool RELU>
__global__ __launch_bounds__(256) void gather_agg(
        const float* __restrict__ T, const int* __restrict__ csr,
        const int* __restrict__ cursor, const int* __restrict__ deg,
        const float* __restrict__ invin, const float* __restrict__ bias,
        float* __restrict__ out, int n_dst) {
    const int wid = (blockIdx.x * blockDim.x + threadIdx.x) >> 6;
    const int lane = threadIdx.x & 63;
    if (wid >= n_dst) return;
    const int cnt = deg[wid];
    const int beg = cursor[wid] - cnt;
    const float sc = invin[wid];
    if (F == 128) {
        float ax = 0.f, ay = 0.f;
        for (int e = 0; e < cnt; ++e) {
            const int s = csr[beg + e];
            const float2 v = *reinterpret_cast<const float2*>(
                T + (size_t)s * F + lane * 2);
            ax += v.x; ay += v.y;
        }
        float ox = ax * sc + bias[lane * 2];
        float oy = ay * sc + bias[lane * 2 + 1];
        float2* po = reinterpret_cast<float2*>(out + (size_t)wid * F + lane * 2);
        if (ACC) { const float2 p = *po; ox += p.x; oy += p.y; }
        if (RELU) { ox = fmaxf(ox, 0.f); oy = fmaxf(oy, 0.f); }
        float2 o; o.x = ox; o.y = oy;
        *po = o;
    } else {
        float a = 0.f;
        for (int e = 0; e < cnt; ++e) {
            const int s = csr[beg + e];
            a += T[(size_t)s * F + lane];
        }
        float o = a * sc + bias[lane];
        if (ACC) o += out[(size_t)wid * F + lane];
        if (RELU) o = fmaxf(o, 0.f);
        out[(size_t)wid * F + lane] = o;
    }
}

extern "C" void kernel_launch(void* const* d_in, const int* in_sizes, int n_in,
                              void* d_out, int out_size, void* d_ws, size_t ws_size,
                              hipStream_t stream) {
    const float* feat_user = (const float*)d_in[0];
    const float* feat_item = (const float*)d_in[1];
    const int* rates_src = (const int*)d_in[2];
    const int* rates_dst = (const int*)d_in[3];
    const int* rated_src = (const int*)d_in[4];
    const int* rated_dst = (const int*)d_in[5];
    const int* fol_src   = (const int*)d_in[6];
    const int* fol_dst   = (const int*)d_in[7];
    const float* W1_rates = (const float*)d_in[8];
    const float* b1_rates = (const float*)d_in[9];
    const float* W1_rated = (const float*)d_in[10];
    const float* b1_rated = (const float*)d_in[11];
    const float* W1_fol   = (const float*)d_in[12];
    const float* b1_fol   = (const float*)d_in[13];
    const float* W2_rates = (const float*)d_in[14];
    const float* b2_rates = (const float*)d_in[15];
    const float* W2_rated = (const float*)d_in[16];
    const float* b2_rated = (const float*)d_in[17];
    const float* W2_fol   = (const float*)d_in[18];
    const float* b2_fol   = (const float*)d_in[19];

    const int n_user = in_sizes[0] / IN_USER;   // 100000
    const int n_item = in_sizes[1] / IN_ITEM;   // 100000
    const int E0 = in_sizes[2];                 // rates edges
    const int E1 = in_sizes[4];                 // rated edges
    const int E2 = in_sizes[6];                 // fol edges
    const int nmax = n_user > n_item ? n_user : n_item;

    // ---- workspace layout ----
    const size_t NP = 100352;  // padded node stride
    int*   deg    = (int*)d_ws;                    // [6][NP]
    float* inv    = (float*)(deg + 6 * NP);        // [6][NP]
    int*   cursor = (int*)(inv + 6 * NP);          // [3][NP]
    int*   csr    = cursor + 3 * NP;               // [E0+E1+E2]
    int*   csr0 = csr;            // rates  (dst = item)
    int*   csr1 = csr + E0;       // rated  (dst = user)
    int*   csr2 = csr + E0 + E1;  // fol    (dst = user)
    // align t to 256B
    size_t toff = ((size_t)(csr + E0 + E1 + E2) + 255) & ~(size_t)255;
    float* t    = (float*)toff;                    // [nmax][HID]
    float* aggU = t + (size_t)nmax * HID;          // [n_user][HID]
    float* aggI = aggU + (size_t)n_user * HID;     // [n_item][HID]

    float* o_user = (float*)d_out;
    float* o_item = o_user + (size_t)n_user * OUTF;

    // degree index map: 0=rates_src(user) 1=rates_dst(item) 2=rated_src(item)
    //                   3=rated_dst(user) 4=fol_src(user)   5=fol_dst(user)
    hipMemsetAsync(deg, 0, 6 * NP * sizeof(int), stream);
    deg_kernel<<<1024, 256, 0, stream>>>(rates_src, rates_dst, deg + 0 * NP, deg + 1 * NP, E0);
    deg_kernel<<<1024, 256, 0, stream>>>(rated_src, rated_dst, deg + 2 * NP, deg + 3 * NP, E1);
    deg_kernel<<<1024, 256, 0, stream>>>(fol_src,   fol_dst,   deg + 4 * NP, deg + 5 * NP, E2);
    inv_kernel<<<1024, 256, 0, stream>>>(deg, inv, (int)(6 * NP));

    // ---- CSR build (by destination) ----
    exscan_kernel<<<1, 1024, 0, stream>>>(deg + 1 * NP, cursor + 0 * NP, n_item);
    exscan_kernel<<<1, 1024, 0, stream>>>(deg + 3 * NP, cursor + 1 * NP, n_user);
    exscan_kernel<<<1, 1024, 0, stream>>>(deg + 5 * NP, cursor + 2 * NP, n_user);
    csr_fill<<<2048, 256, 0, stream>>>(rates_src, rates_dst, cursor + 0 * NP, csr0, E0);
    csr_fill<<<2048, 256, 0, stream>>>(rated_src, rated_dst, cursor + 1 * NP, csr1, E1);
    csr_fill<<<2048, 256, 0, stream>>>(fol_src,   fol_dst,   cursor + 2 * NP, csr2, E2);
    // after fill: cursor[v] = end of node v's range; begin = cursor[v]-deg[v]

    const int gwU = (n_user * 64 + 255) / 256;   // gather grid (1 wave/node)
    const int gwI = (n_item * 64 + 255) / 256;
    dim3 gU1((n_user + 63) / 64, HID / 64);
    dim3 gI1((n_item + 63) / 64, HID / 64);
    dim3 gU2((n_user + 63) / 64, OUTF / 64);
    dim3 gI2((n_item + 63) / 64, OUTF / 64);

    // ---- layer 1 ----
    gemm_scale<IN_USER, HID><<<gU1, 256, 0, stream>>>(feat_user, W1_rates, inv + 0 * NP, t, n_user);
    gather_agg<HID, false, true><<<gwI, 256, 0, stream>>>(
        t, csr0, cursor + 0 * NP, deg + 1 * NP, inv + 1 * NP, b1_rates, aggI, n_item);

    gemm_scale<IN_ITEM, HID><<<gI1, 256, 0, stream>>>(feat_item, W1_rated, inv + 2 * NP, t, n_item);
    gather_agg<HID, false, false><<<gwU, 256, 0, stream>>>(
        t, csr1, cursor + 1 * NP, deg + 3 * NP, inv + 3 * NP, b1_rated, aggU, n_user);

    gemm_scale<IN_USER, HID><<<gU1, 256, 0, stream>>>(feat_user, W1_fol, inv + 4 * NP, t, n_user);
    gather_agg<HID, true, true><<<gwU, 256, 0, stream>>>(
        t, csr2, cursor + 2 * NP, deg + 5 * NP, inv + 5 * NP, b1_fol, aggU, n_user);

    // ---- layer 2 (straight into d_out) ----
    gemm_scale<HID, OUTF><<<gU2, 256, 0, stream>>>(aggU, W2_rates, inv + 0 * NP, t, n_user);
    gather_agg<OUTF, false, false><<<gwI, 256, 0, stream>>>(
        t, csr0, cursor + 0 * NP, deg + 1 * NP, inv + 1 * NP, b2_rates, o_item, n_item);

    gemm_scale<HID, OUTF><<<gI2, 256, 0, stream>>>(aggI, W2_rated, inv + 2 * NP, t, n_item);
    gather_agg<OUTF, false, false><<<gwU, 256, 0, stream>>>(
        t, csr1, cursor + 1 * NP, deg + 3 * NP, inv + 3 * NP, b2_rated, o_user, n_user);

    gemm_scale<HID, OUTF><<<gU2, 256, 0, stream>>>(aggU, W2_fol, inv + 4 * NP, t, n_user);
    gather_agg<OUTF, true, false><<<gwU, 256, 0, stream>>>(
        t, csr2, cursor + 2 * NP, deg + 5 * NP, inv + 5 * NP, b2_fol, o_user, n_user);
}

// Round 3
// 1268.355 us; speedup vs baseline: 5.2484x; 1.3648x over previous
//
#include <hip/hip_runtime.h>
#include <math.h>

#define IN_USER 256
#define IN_ITEM 128
#define HID 128
#define OUTF 64

// ---------------- degree histogram ----------------
__global__ __launch_bounds__(256) void deg_kernel(
        const int* __restrict__ src, const int* __restrict__ dst,
        int* __restrict__ degs, int* __restrict__ degd, int E) {
    const int stride = gridDim.x * blockDim.x;
    for (int i = blockIdx.x * blockDim.x + threadIdx.x; i < E; i += stride) {
        atomicAdd(&degs[src[i]], 1);
        atomicAdd(&degd[dst[i]], 1);
    }
}

__global__ __launch_bounds__(256) void inv_kernel(
        const int* __restrict__ deg, float* __restrict__ inv, int n) {
    const int stride = gridDim.x * blockDim.x;
    for (int i = blockIdx.x * blockDim.x + threadIdx.x; i < n; i += stride) {
        const int d = deg[i];
        inv[i] = 1.0f / sqrtf((float)(d > 1 ? d : 1));
    }
}

// ---------------- device-wide exclusive scan, batched over 3 relations ----
// pass 1: per-block sums (block = 1024 elements)
__global__ __launch_bounds__(256) void scan_part(
        const int* __restrict__ d0, const int* __restrict__ d1,
        const int* __restrict__ d2, int n0, int n1, int n2,
        int* __restrict__ partial, int nblk) {
    const int rel = blockIdx.y;
    const int* deg = rel == 0 ? d0 : (rel == 1 ? d1 : d2);
    const int n = rel == 0 ? n0 : (rel == 1 ? n1 : n2);
    const int base = blockIdx.x * 1024 + threadIdx.x * 4;
    int s = 0;
#pragma unroll
    for (int i = 0; i < 4; ++i) {
        const int idx = base + i;
        if (idx < n) s += deg[idx];
    }
    __shared__ int red[256];
    red[threadIdx.x] = s;
    __syncthreads();
#pragma unroll
    for (int off = 128; off > 0; off >>= 1) {
        if (threadIdx.x < off) red[threadIdx.x] += red[threadIdx.x + off];
        __syncthreads();
    }
    if (threadIdx.x == 0) partial[rel * nblk + blockIdx.x] = red[0];
}

// pass 2: exclusive-scan the per-block sums (nblk <= 128)
__global__ __launch_bounds__(128) void scan_mid(int* __restrict__ partial, int nblk) {
    __shared__ int sc[128];
    const int rel = blockIdx.x;
    const int t = threadIdx.x;
    const int v = (t < nblk) ? partial[rel * nblk + t] : 0;
    sc[t] = v;
    __syncthreads();
    for (int off = 1; off < 128; off <<= 1) {
        const int u = (t >= off) ? sc[t - off] : 0;
        __syncthreads();
        sc[t] += u;
        __syncthreads();
    }
    if (t < nblk) partial[rel * nblk + t] = sc[t] - v;   // exclusive
}

// pass 3: local rescan + block offset -> cursor (= start of each node's range)
__global__ __launch_bounds__(256) void scan_final(
        const int* __restrict__ d0, const int* __restrict__ d1,
        const int* __restrict__ d2, int n0, int n1, int n2,
        const int* __restrict__ partial,
        int* __restrict__ c0, int* __restrict__ c1, int* __restrict__ c2,
        int nblk) {
    const int rel = blockIdx.y;
    const int* deg = rel == 0 ? d0 : (rel == 1 ? d1 : d2);
    int* cur = rel == 0 ? c0 : (rel == 1 ? c1 : c2);
    const int n = rel == 0 ? n0 : (rel == 1 ? n1 : n2);
    const int base = blockIdx.x * 1024 + threadIdx.x * 4;
    int v[4];
    int s = 0;
#pragma unroll
    for (int i = 0; i < 4; ++i) {
        const int idx = base + i;
        v[i] = (idx < n) ? deg[idx] : 0;
        s += v[i];
    }
    __shared__ int sc[256];
    sc[threadIdx.x] = s;
    __syncthreads();
    for (int off = 1; off < 256; off <<= 1) {
        const int u = (threadIdx.x >= off) ? sc[threadIdx.x - off] : 0;
        __syncthreads();
        sc[threadIdx.x] += u;
        __syncthreads();
    }
    int run = (threadIdx.x == 0 ? 0 : sc[threadIdx.x - 1]) + partial[rel * nblk + blockIdx.x];
#pragma unroll
    for (int i = 0; i < 4; ++i) {
        const int idx = base + i;
        if (idx < n) cur[idx] = run;
        run += v[i];
    }
}

// ---------------- CSR fill: csr[pos] = src, pos = cursor[dst]++ ----------------
__global__ __launch_bounds__(256) void csr_fill(
        const int* __restrict__ src, const int* __restrict__ dst,
        int* __restrict__ cursor, int* __restrict__ csr, int E) {
    const int stride = gridDim.x * blockDim.x;
    for (int i = blockIdx.x * blockDim.x + threadIdx.x; i < E; i += stride) {
        const int pos = atomicAdd(&cursor[dst[i]], 1);
        csr[pos] = src[i];
    }
}

// ------------- T = (X @ W) * invout[:,None] -------------
// 64x64 output tile per 256-thread block, BK=16, 4x4 per thread, fp32.
template<int K, int N>
__global__ __launch_bounds__(256) void gemm_scale(
        const float* __restrict__ X, const float* __restrict__ W,
        const float* __restrict__ invout, float* __restrict__ T, int M) {
    __shared__ float xs[16][64];   // xs[k][m] = X[row0+m][kk+k]
    __shared__ float ws[16][64];   // ws[k][n] = W[kk+k][col0+n]
    const int row0 = blockIdx.x * 64;
    const int col0 = blockIdx.y * 64;
    const int tid = threadIdx.x;
    const int tm = (tid >> 4) * 4;
    const int tn = (tid & 15) * 4;
    const int xr = tid >> 2;           // 0..63 row in tile
    const int xc = (tid & 3) * 4;      // 0,4,8,12 col chunk
    const int wk = tid >> 4;           // 0..15
    const int wc = (tid & 15) * 4;     // 0..60
    float acc[4][4] = {};
    for (int kk = 0; kk < K; kk += 16) {
        float4 xv = make_float4(0.f, 0.f, 0.f, 0.f);
        const int xrow = row0 + xr;
        if (xrow < M)
            xv = *reinterpret_cast<const float4*>(X + (size_t)xrow * K + kk + xc);
        const float4 wv = *reinterpret_cast<const float4*>(
            W + (size_t)(kk + wk) * N + col0 + wc);
        __syncthreads();               // previous iter's LDS reads done
        xs[xc + 0][xr] = xv.x; xs[xc + 1][xr] = xv.y;
        xs[xc + 2][xr] = xv.z; xs[xc + 3][xr] = xv.w;
        ws[wk][wc + 0] = wv.x; ws[wk][wc + 1] = wv.y;
        ws[wk][wc + 2] = wv.z; ws[wk][wc + 3] = wv.w;
        __syncthreads();
#pragma unroll
        for (int k = 0; k < 16; ++k) {
            const float4 a = *reinterpret_cast<const float4*>(&xs[k][tm]);
            const float4 b = *reinterpret_cast<const float4*>(&ws[k][tn]);
            acc[0][0] += a.x * b.x; acc[0][1] += a.x * b.y;
            acc[0][2] += a.x * b.z; acc[0][3] += a.x * b.w;
            acc[1][0] += a.y * b.x; acc[1][1] += a.y * b.y;
            acc[1][2] += a.y * b.z; acc[1][3] += a.y * b.w;
            acc[2][0] += a.z * b.x; acc[2][1] += a.z * b.y;
            acc[2][2] += a.z * b.z; acc[2][3] += a.z * b.w;
            acc[3][0] += a.w * b.x; acc[3][1] += a.w * b.y;
            acc[3][2] += a.w * b.z; acc[3][3] += a.w * b.w;
        }
    }
#pragma unroll
    for (int i = 0; i < 4; ++i) {
        const int row = row0 + tm + i;
        if (row < M) {
            const float s = invout[row];
            float4 o;
            o.x = acc[i][0] * s; o.y = acc[i][1] * s;
            o.z = acc[i][2] * s; o.w = acc[i][3] * s;
            *reinterpret_cast<float4*>(T + (size_t)row * N + col0 + tn) = o;
        }
    }
}

// ------------- pull-aggregation: one wave per dst node -------------
template<int F, bool ACC, bool RELU>
__global__ __launch_bounds__(256) void gather_agg(
        const float* __restrict__ T, const int* __restrict__ csr,
        const int* __restrict__ cursor, const int* __restrict__ deg,
        const float* __restrict__ invin, const float* __restrict__ bias,
        float* __restrict__ out, int n_dst) {
    const int wid = (blockIdx.x * blockDim.x + threadIdx.x) >> 6;
    const int lane = threadIdx.x & 63;
    if (wid >= n_dst) return;
    const int cnt = deg[wid];
    const int beg = cursor[wid] - cnt;
    const float sc = invin[wid];
    if (F == 128) {
        float ax = 0.f, ay = 0.f;
        for (int e = 0; e < cnt; ++e) {
            const int s = csr[beg + e];
            const float2 v = *reinterpret_cast<const float2*>(
                T + (size_t)s * F + lane * 2);
            ax += v.x; ay += v.y;
        }
        float ox = ax * sc + bias[lane * 2];
        float oy = ay * sc + bias[lane * 2 + 1];
        float2* po = reinterpret_cast<float2*>(out + (size_t)wid * F + lane * 2);
        if (ACC) { const float2 p = *po; ox += p.x; oy += p.y; }
        if (RELU) { ox = fmaxf(ox, 0.f); oy = fmaxf(oy, 0.f); }
        float2 o; o.x = ox; o.y = oy;
        *po = o;
    } else {
        float a = 0.f;
        for (int e = 0; e < cnt; ++e) {
            const int s = csr[beg + e];
            a += T[(size_t)s * F + lane];
        }
        float o = a * sc + bias[lane];
        if (ACC) o += out[(size_t)wid * F + lane];
        if (RELU) o = fmaxf(o, 0.f);
        out[(size_t)wid * F + lane] = o;
    }
}

extern "C" void kernel_launch(void* const* d_in, const int* in_sizes, int n_in,
                              void* d_out, int out_size, void* d_ws, size_t ws_size,
                              hipStream_t stream) {
    const float* feat_user = (const float*)d_in[0];
    const float* feat_item = (const float*)d_in[1];
    const int* rates_src = (const int*)d_in[2];
    const int* rates_dst = (const int*)d_in[3];
    const int* rated_src = (const int*)d_in[4];
    const int* rated_dst = (const int*)d_in[5];
    const int* fol_src   = (const int*)d_in[6];
    const int* fol_dst   = (const int*)d_in[7];
    const float* W1_rates = (const float*)d_in[8];
    const float* b1_rates = (const float*)d_in[9];
    const float* W1_rated = (const float*)d_in[10];
    const float* b1_rated = (const float*)d_in[11];
    const float* W1_fol   = (const float*)d_in[12];
    const float* b1_fol   = (const float*)d_in[13];
    const float* W2_rates = (const float*)d_in[14];
    const float* b2_rates = (const float*)d_in[15];
    const float* W2_rated = (const float*)d_in[16];
    const float* b2_rated = (const float*)d_in[17];
    const float* W2_fol   = (const float*)d_in[18];
    const float* b2_fol   = (const float*)d_in[19];

    const int n_user = in_sizes[0] / IN_USER;   // 100000
    const int n_item = in_sizes[1] / IN_ITEM;   // 100000
    const int E0 = in_sizes[2];                 // rates edges
    const int E1 = in_sizes[4];                 // rated edges
    const int E2 = in_sizes[6];                 // fol edges
    const int nmax = n_user > n_item ? n_user : n_item;

    // ---- workspace layout ----
    const size_t NP = 100352;  // padded node stride (= 98*1024)
    int*   deg    = (int*)d_ws;                    // [6][NP]
    float* inv    = (float*)(deg + 6 * NP);        // [6][NP]
    int*   cursor = (int*)(inv + 6 * NP);          // [3][NP]
    int*   partial = cursor + 3 * NP;              // [3][128]
    int*   csr    = partial + 3 * 128;             // [E0+E1+E2]
    int*   csr0 = csr;            // rates  (dst = item)
    int*   csr1 = csr + E0;       // rated  (dst = user)
    int*   csr2 = csr + E0 + E1;  // fol    (dst = user)
    size_t toff = ((size_t)(csr + E0 + E1 + E2) + 255) & ~(size_t)255;
    float* t    = (float*)toff;                    // [nmax][HID]
    float* aggU = t + (size_t)nmax * HID;          // [n_user][HID]
    float* aggI = aggU + (size_t)n_user * HID;     // [n_item][HID]

    float* o_user = (float*)d_out;
    float* o_item = o_user + (size_t)n_user * OUTF;

    // degree index map: 0=rates_src(user) 1=rates_dst(item) 2=rated_src(item)
    //                   3=rated_dst(user) 4=fol_src(user)   5=fol_dst(user)
    hipMemsetAsync(deg, 0, 6 * NP * sizeof(int), stream);
    deg_kernel<<<1024, 256, 0, stream>>>(rates_src, rates_dst, deg + 0 * NP, deg + 1 * NP, E0);
    deg_kernel<<<1024, 256, 0, stream>>>(rated_src, rated_dst, deg + 2 * NP, deg + 3 * NP, E1);
    deg_kernel<<<1024, 256, 0, stream>>>(fol_src,   fol_dst,   deg + 4 * NP, deg + 5 * NP, E2);
    inv_kernel<<<1024, 256, 0, stream>>>(deg, inv, (int)(6 * NP));

    // ---- CSR build (by destination): batched 3-pass exclusive scan ----
    const int nblk = (nmax + 1023) / 1024;   // 98 (<=128 required by scan_mid)
    scan_part<<<dim3(nblk, 3), 256, 0, stream>>>(
        deg + 1 * NP, deg + 3 * NP, deg + 5 * NP, n_item, n_user, n_user, partial, nblk);
    scan_mid<<<3, 128, 0, stream>>>(partial, nblk);
    scan_final<<<dim3(nblk, 3), 256, 0, stream>>>(
        deg + 1 * NP, deg + 3 * NP, deg + 5 * NP, n_item, n_user, n_user, partial,
        cursor + 0 * NP, cursor + 1 * NP, cursor + 2 * NP, nblk);

    csr_fill<<<2048, 256, 0, stream>>>(rates_src, rates_dst, cursor + 0 * NP, csr0, E0);
    csr_fill<<<2048, 256, 0, stream>>>(rated_src, rated_dst, cursor + 1 * NP, csr1, E1);
    csr_fill<<<2048, 256, 0, stream>>>(fol_src,   fol_dst,   cursor + 2 * NP, csr2, E2);
    // after fill: cursor[v] = end of node v's range; begin = cursor[v]-deg[v]

    const int gwU = (n_user * 64 + 255) / 256;   // gather grid (1 wave/node)
    const int gwI = (n_item * 64 + 255) / 256;
    dim3 gU1((n_user + 63) / 64, HID / 64);
    dim3 gI1((n_item + 63) / 64, HID / 64);
    dim3 gU2((n_user + 63) / 64, OUTF / 64);
    dim3 gI2((n_item + 63) / 64, OUTF / 64);

    // ---- layer 1 ----
    gemm_scale<IN_USER, HID><<<gU1, 256, 0, stream>>>(feat_user, W1_rates, inv + 0 * NP, t, n_user);
    gather_agg<HID, false, true><<<gwI, 256, 0, stream>>>(
        t, csr0, cursor + 0 * NP, deg + 1 * NP, inv + 1 * NP, b1_rates, aggI, n_item);

    gemm_scale<IN_ITEM, HID><<<gI1, 256, 0, stream>>>(feat_item, W1_rated, inv + 2 * NP, t, n_item);
    gather_agg<HID, false, false><<<gwU, 256, 0, stream>>>(
        t, csr1, cursor + 1 * NP, deg + 3 * NP, inv + 3 * NP, b1_rated, aggU, n_user);

    gemm_scale<IN_USER, HID><<<gU1, 256, 0, stream>>>(feat_user, W1_fol, inv + 4 * NP, t, n_user);
    gather_agg<HID, true, true><<<gwU, 256, 0, stream>>>(
        t, csr2, cursor + 2 * NP, deg + 5 * NP, inv + 5 * NP, b1_fol, aggU, n_user);

    // ---- layer 2 (straight into d_out) ----
    gemm_scale<HID, OUTF><<<gU2, 256, 0, stream>>>(aggU, W2_rates, inv + 0 * NP, t, n_user);
    gather_agg<OUTF, false, false><<<gwI, 256, 0, stream>>>(
        t, csr0, cursor + 0 * NP, deg + 1 * NP, inv + 1 * NP, b2_rates, o_item, n_item);

    gemm_scale<HID, OUTF><<<gI2, 256, 0, stream>>>(aggI, W2_rated, inv + 2 * NP, t, n_item);
    gather_agg<OUTF, false, false><<<gwU, 256, 0, stream>>>(
        t, csr1, cursor + 1 * NP, deg + 3 * NP, inv + 3 * NP, b2_rated, o_user, n_user);

    gemm_scale<HID, OUTF><<<gU2, 256, 0, stream>>>(aggU, W2_fol, inv + 4 * NP, t, n_user);
    gather_agg<OUTF, true, false><<<gwU, 256, 0, stream>>>(
        t, csr2, cursor + 2 * NP, deg + 5 * NP, inv + 5 * NP, b2_fol, o_user, n_user);
}

// Round 4
// 1004.965 us; speedup vs baseline: 6.6239x; 1.2621x over previous
//
#include <hip/hip_runtime.h>
#include <math.h>

#define IN_USER 256
#define IN_ITEM 128
#define HID 128
#define OUTF 64

typedef unsigned short u16;
typedef unsigned int u32;
typedef __attribute__((ext_vector_type(8))) __bf16 bf16x8;
typedef __attribute__((ext_vector_type(4))) float f32x4;

__device__ __forceinline__ u16 f2bf(float f) {
    union { float f; u32 u; } c; c.f = f;
    return (u16)((c.u + 0x7fffu + ((c.u >> 16) & 1u)) >> 16);
}
__device__ __forceinline__ float bf2f(u16 h) {
    union { u32 u; float f; } c; c.u = ((u32)h) << 16;
    return c.f;
}
__device__ __forceinline__ u32 pack2(float a, float b) {
    return (u32)f2bf(a) | ((u32)f2bf(b) << 16);
}

// ---------------- degree histogram ----------------
__global__ __launch_bounds__(256) void deg_kernel(
        const int* __restrict__ src, const int* __restrict__ dst,
        int* __restrict__ degs, int* __restrict__ degd, int E) {
    const int stride = gridDim.x * blockDim.x;
    for (int i = blockIdx.x * blockDim.x + threadIdx.x; i < E; i += stride) {
        atomicAdd(&degs[src[i]], 1);
        atomicAdd(&degd[dst[i]], 1);
    }
}

__global__ __launch_bounds__(256) void inv_kernel(
        const int* __restrict__ deg, float* __restrict__ inv, int n) {
    const int stride = gridDim.x * blockDim.x;
    for (int i = blockIdx.x * blockDim.x + threadIdx.x; i < n; i += stride) {
        const int d = deg[i];
        inv[i] = 1.0f / sqrtf((float)(d > 1 ? d : 1));
    }
}

// ---------------- device-wide exclusive scan (3 relations batched) ------
__global__ __launch_bounds__(256) void scan_part(
        const int* __restrict__ d0, const int* __restrict__ d1,
        const int* __restrict__ d2, int n0, int n1, int n2,
        int* __restrict__ partial, int nblk) {
    const int rel = blockIdx.y;
    const int* deg = rel == 0 ? d0 : (rel == 1 ? d1 : d2);
    const int n = rel == 0 ? n0 : (rel == 1 ? n1 : n2);
    const int base = blockIdx.x * 1024 + threadIdx.x * 4;
    int s = 0;
#pragma unroll
    for (int i = 0; i < 4; ++i) {
        const int idx = base + i;
        if (idx < n) s += deg[idx];
    }
    __shared__ int red[256];
    red[threadIdx.x] = s;
    __syncthreads();
#pragma unroll
    for (int off = 128; off > 0; off >>= 1) {
        if (threadIdx.x < off) red[threadIdx.x] += red[threadIdx.x + off];
        __syncthreads();
    }
    if (threadIdx.x == 0) partial[rel * nblk + blockIdx.x] = red[0];
}

__global__ __launch_bounds__(128) void scan_mid(int* __restrict__ partial, int nblk) {
    __shared__ int sc[128];
    const int rel = blockIdx.x;
    const int t = threadIdx.x;
    const int v = (t < nblk) ? partial[rel * nblk + t] : 0;
    sc[t] = v;
    __syncthreads();
    for (int off = 1; off < 128; off <<= 1) {
        const int u = (t >= off) ? sc[t - off] : 0;
        __syncthreads();
        sc[t] += u;
        __syncthreads();
    }
    if (t < nblk) partial[rel * nblk + t] = sc[t] - v;
}

__global__ __launch_bounds__(256) void scan_final(
        const int* __restrict__ d0, const int* __restrict__ d1,
        const int* __restrict__ d2, int n0, int n1, int n2,
        const int* __restrict__ partial,
        int* __restrict__ c0, int* __restrict__ c1, int* __restrict__ c2,
        int nblk) {
    const int rel = blockIdx.y;
    const int* deg = rel == 0 ? d0 : (rel == 1 ? d1 : d2);
    int* cur = rel == 0 ? c0 : (rel == 1 ? c1 : c2);
    const int n = rel == 0 ? n0 : (rel == 1 ? n1 : n2);
    const int base = blockIdx.x * 1024 + threadIdx.x * 4;
    int v[4];
    int s = 0;
#pragma unroll
    for (int i = 0; i < 4; ++i) {
        const int idx = base + i;
        v[i] = (idx < n) ? deg[idx] : 0;
        s += v[i];
    }
    __shared__ int sc[256];
    sc[threadIdx.x] = s;
    __syncthreads();
    for (int off = 1; off < 256; off <<= 1) {
        const int u = (threadIdx.x >= off) ? sc[threadIdx.x - off] : 0;
        __syncthreads();
        sc[threadIdx.x] += u;
        __syncthreads();
    }
    int run = (threadIdx.x == 0 ? 0 : sc[threadIdx.x - 1]) + partial[rel * nblk + blockIdx.x];
#pragma unroll
    for (int i = 0; i < 4; ++i) {
        const int idx = base + i;
        if (idx < n) cur[idx] = run;
        run += v[i];
    }
}

__global__ __launch_bounds__(256) void csr_fill(
        const int* __restrict__ src, const int* __restrict__ dst,
        int* __restrict__ cursor, int* __restrict__ csr, int E) {
    const int stride = gridDim.x * blockDim.x;
    for (int i = blockIdx.x * blockDim.x + threadIdx.x; i < E; i += stride) {
        const int pos = atomicAdd(&cursor[dst[i]], 1);
        csr[pos] = src[i];
    }
}

// -------- weight transpose + concat: dst[n][k] (bf16) from src[k][n] fp32 --
__global__ __launch_bounds__(256) void wt_kernel(
        u16* __restrict__ dst, const float* __restrict__ s0,
        const float* __restrict__ s1, int K, int N0, int N1) {
    const int i = blockIdx.x * 256 + threadIdx.x;
    const int tot = K * (N0 + N1);
    if (i >= tot) return;
    const int n = i / K, k = i - n * K;
    const float v = (n < N0) ? s0[k * N0 + n] : s1[k * N1 + (n - N0)];
    dst[(size_t)n * K + k] = f2bf(v);
}

// -------- MFMA GEMM: T = bf16((X @ Wt^T) * inv[:,None]) --------
// X: [M][K] (fp32 or bf16 per A_BF16); Wt: [N][K] bf16 (pre-transposed).
// BM=128, BK=64, BN in {128,64}; 2*BN/64 waves; wave tile 64x64 (4x4 frags).
// Columns >= nsplit scale with invB, else invA.
// LDS XOR-swizzle: element (row,k) at row*64 + (((k>>3)^(row&7))<<3) + (k&7).
template<int K, int BN, bool A_BF16>
__global__ __launch_bounds__(BN * 2) void gemm_mfma(
        const void* __restrict__ Xv, const u16* __restrict__ Wt,
        const float* __restrict__ invA, const float* __restrict__ invB,
        int nsplit, u16* __restrict__ T, int M, int TN) {
    constexpr int BLK = BN * 2;
    constexpr int WN = BN / 64;
    constexpr int CA = 1024 / BLK;       // A chunks (128 rows * 8) per thread
    constexpr int CB = (BN * 8) / BLK;   // B chunks per thread
    __shared__ u16 lA[128 * 64];
    __shared__ u16 lB[BN * 64];

    const int tid = threadIdx.x;
    const int row0 = blockIdx.x * 128;
    const int col0 = blockIdx.y * BN;
    const int wid = tid >> 6, lane = tid & 63;
    const int wm = wid / WN, wn = wid % WN;
    const int l15 = lane & 15, lhi = lane >> 4;

    f32x4 acc[4][4] = {};

    for (int kk = 0; kk < K; kk += 64) {
        __syncthreads();
        // ---- stage A (fp32->bf16 convert or bf16 copy) ----
#pragma unroll
        for (int c = 0; c < CA; ++c) {
            const int cid = tid + c * BLK;
            const int row = cid >> 3, kc = cid & 7;
            const int grow = row0 + row;
            uint4 u = make_uint4(0, 0, 0, 0);
            if (A_BF16) {
                if (grow < M)
                    u = *reinterpret_cast<const uint4*>(
                        (const u16*)Xv + (size_t)grow * K + kk + kc * 8);
            } else {
                if (grow < M) {
                    const float* xp = (const float*)Xv + (size_t)grow * K + kk + kc * 8;
                    const float4 v0 = *reinterpret_cast<const float4*>(xp);
                    const float4 v1 = *reinterpret_cast<const float4*>(xp + 4);
                    u.x = pack2(v0.x, v0.y); u.y = pack2(v0.z, v0.w);
                    u.z = pack2(v1.x, v1.y); u.w = pack2(v1.z, v1.w);
                }
            }
            const int e = row * 64 + ((kc ^ (row & 7)) << 3);
            *reinterpret_cast<uint4*>(&lA[e]) = u;
        }
        // ---- stage B (bf16 copy from Wt[n][k]) ----
#pragma unroll
        for (int c = 0; c < CB; ++c) {
            const int cid = tid + c * BLK;
            const int n = cid >> 3, kc = cid & 7;
            const uint4 u = *reinterpret_cast<const uint4*>(
                Wt + (size_t)(col0 + n) * K + kk + kc * 8);
            const int e = n * 64 + ((kc ^ (n & 7)) << 3);
            *reinterpret_cast<uint4*>(&lB[e]) = u;
        }
        __syncthreads();
        // ---- MFMA ----
#pragma unroll
        for (int ks = 0; ks < 2; ++ks) {
            const int cb = ks * 4 + lhi;   // k>>3
            bf16x8 af[4], bfr[4];
#pragma unroll
            for (int fm = 0; fm < 4; ++fm) {
                const int r = wm * 64 + fm * 16 + l15;
                const uint4 u = *reinterpret_cast<const uint4*>(
                    &lA[r * 64 + ((cb ^ (r & 7)) << 3)]);
                af[fm] = __builtin_bit_cast(bf16x8, u);
            }
#pragma unroll
            for (int fn = 0; fn < 4; ++fn) {
                const int r = wn * 64 + fn * 16 + l15;
                const uint4 u = *reinterpret_cast<const uint4*>(
                    &lB[r * 64 + ((cb ^ (r & 7)) << 3)]);
                bfr[fn] = __builtin_bit_cast(bf16x8, u);
            }
#pragma unroll
            for (int fm = 0; fm < 4; ++fm)
#pragma unroll
                for (int fn = 0; fn < 4; ++fn)
                    acc[fm][fn] = __builtin_amdgcn_mfma_f32_16x16x32_bf16(
                        af[fm], bfr[fn], acc[fm][fn], 0, 0, 0);
        }
    }

    // ---- epilogue: scale by inv, convert to bf16, store ----
    const int colw = col0 + wn * 64;
    const float* invp = (colw >= nsplit) ? invB : invA;
#pragma unroll
    for (int fm = 0; fm < 4; ++fm) {
#pragma unroll
        for (int r4 = 0; r4 < 4; ++r4) {
            const int grow = row0 + wm * 64 + fm * 16 + lhi * 4 + r4;
            if (grow < M) {
                const float s = invp[grow];
#pragma unroll
                for (int fn = 0; fn < 4; ++fn) {
                    const int col = colw + fn * 16 + l15;
                    T[(size_t)grow * TN + col] = f2bf(acc[fm][fn][r4] * s);
                }
            }
        }
    }
}

// -------- pull-aggregation over bf16 T, one wave per dst node -----------
// r = sumA(T_a rows)*invA + biasA [+ sumB(T_b rows)*invB + biasB]; opt ReLU;
// out bf16 (layer1 agg) or fp32 (final output).
template<int F, bool TWO, bool RELU, bool BF16OUT>
__global__ __launch_bounds__(256) void gather(
        const u16* __restrict__ Ta, int strideA, int offA,
        const int* __restrict__ csrA, const int* __restrict__ curA,
        const int* __restrict__ degA, const float* __restrict__ invA,
        const float* __restrict__ biasA,
        const u16* __restrict__ Tb, int strideB, int offB,
        const int* __restrict__ csrB, const int* __restrict__ curB,
        const int* __restrict__ degB, const float* __restrict__ invB,
        const float* __restrict__ biasB,
        void* __restrict__ outv, int n) {
    const int wid = (blockIdx.x * 256 + threadIdx.x) >> 6;
    const int lane = threadIdx.x & 63;
    if (wid >= n) return;
    float r0, r1 = 0.f;
    {
        const int cnt = degA[wid];
        const int beg = curA[wid] - cnt;
        float s0 = 0.f, s1 = 0.f;
        for (int e = 0; e < cnt; ++e) {
            const int s = csrA[beg + e];
            if (F == 128) {
                const u32 v = *reinterpret_cast<const u32*>(
                    Ta + (size_t)s * strideA + offA + lane * 2);
                s0 += bf2f((u16)v); s1 += bf2f((u16)(v >> 16));
            } else {
                s0 += bf2f(Ta[(size_t)s * strideA + offA + lane]);
            }
        }
        const float a = invA[wid];
        if (F == 128) {
            const float2 b = *reinterpret_cast<const float2*>(biasA + lane * 2);
            r0 = s0 * a + b.x; r1 = s1 * a + b.y;
        } else {
            r0 = s0 * a + biasA[lane];
        }
    }
    if (TWO) {
        const int cnt = degB[wid];
        const int beg = curB[wid] - cnt;
        float s0 = 0.f, s1 = 0.f;
        for (int e = 0; e < cnt; ++e) {
            const int s = csrB[beg + e];
            if (F == 128) {
                const u32 v = *reinterpret_cast<const u32*>(
                    Tb + (size_t)s * strideB + offB + lane * 2);
                s0 += bf2f((u16)v); s1 += bf2f((u16)(v >> 16));
            } else {
                s0 += bf2f(Tb[(size_t)s * strideB + offB + lane]);
            }
        }
        const float a = invB[wid];
        if (F == 128) {
            const float2 b = *reinterpret_cast<const float2*>(biasB + lane * 2);
            r0 += s0 * a + b.x; r1 += s1 * a + b.y;
        } else {
            r0 += s0 * a + biasB[lane];
        }
    }
    if (RELU) { r0 = fmaxf(r0, 0.f); r1 = fmaxf(r1, 0.f); }
    if (BF16OUT) {
        if (F == 128)
            ((u32*)outv)[(size_t)wid * 64 + lane] = pack2(r0, r1);
        else
            ((u16*)outv)[(size_t)wid * 64 + lane] = f2bf(r0);
    } else {
        if (F == 128) {
            float2 o; o.x = r0; o.y = r1;
            *reinterpret_cast<float2*>((float*)outv + (size_t)wid * 128 + lane * 2) = o;
        } else {
            ((float*)outv)[(size_t)wid * 64 + lane] = r0;
        }
    }
}

extern "C" void kernel_launch(void* const* d_in, const int* in_sizes, int n_in,
                              void* d_out, int out_size, void* d_ws, size_t ws_size,
                              hipStream_t stream) {
    const float* feat_user = (const float*)d_in[0];
    const float* feat_item = (const float*)d_in[1];
    const int* rates_src = (const int*)d_in[2];
    const int* rates_dst = (const int*)d_in[3];
    const int* rated_src = (const int*)d_in[4];
    const int* rated_dst = (const int*)d_in[5];
    const int* fol_src   = (const int*)d_in[6];
    const int* fol_dst   = (const int*)d_in[7];
    const float* W1_rates = (const float*)d_in[8];
    const float* b1_rates = (const float*)d_in[9];
    const float* W1_rated = (const float*)d_in[10];
    const float* b1_rated = (const float*)d_in[11];
    const float* W1_fol   = (const float*)d_in[12];
    const float* b1_fol   = (const float*)d_in[13];
    const float* W2_rates = (const float*)d_in[14];
    const float* b2_rates = (const float*)d_in[15];
    const float* W2_rated = (const float*)d_in[16];
    const float* b2_rated = (const float*)d_in[17];
    const float* W2_fol   = (const float*)d_in[18];
    const float* b2_fol   = (const float*)d_in[19];

    const int n_user = in_sizes[0] / IN_USER;   // 100000
    const int n_item = in_sizes[1] / IN_ITEM;   // 100000
    const int E0 = in_sizes[2];
    const int E1 = in_sizes[4];
    const int E2 = in_sizes[6];
    const int nmax = n_user > n_item ? n_user : n_item;

    // ---- workspace layout ----
    const size_t NP = ((size_t)(nmax + 1023) / 1024) * 1024;   // 100352
    int*   deg     = (int*)d_ws;                   // [6][NP]
    float* inv     = (float*)(deg + 6 * NP);       // [6][NP]
    int*   cursor  = (int*)(inv + 6 * NP);         // [3][NP]
    int*   partial = cursor + 3 * NP;              // [3][128]
    int*   csr     = partial + 3 * 128;
    int*   csr0 = csr;            // rates (dst=item)
    int*   csr1 = csr + E0;       // rated (dst=user)
    int*   csr2 = csr + E0 + E1;  // fol   (dst=user)
    u16* Wt1u = (u16*)(csr + E0 + E1 + E2);        // [256][256]
    u16* Wt1i = Wt1u + 256 * 256;                  // [128][128]
    u16* Wt2u = Wt1i + 128 * 128;                  // [128][128]
    u16* Wt2i = Wt2u + 128 * 128;                  // [64][128]
    u16* t1u  = Wt2i + 64 * 128;                   // [nmax][256] bf16
    u16* t1i  = t1u + (size_t)nmax * 256;          // [nmax][128] bf16
    u16* aggU = t1i + (size_t)nmax * 128;          // [n_user][128] bf16
    u16* aggI = aggU + (size_t)nmax * 128;         // [n_item][128] bf16
    u16* t2u  = t1i;   // alias: t1i dead after user_L1 gather
    u16* t2i  = t1u;   // alias: t1u dead after user_L1 gather

    float* o_user = (float*)d_out;
    float* o_item = o_user + (size_t)n_user * OUTF;

    // inv idx: 0=rates_src(user) 1=rates_dst(item) 2=rated_src(item)
    //          3=rated_dst(user) 4=fol_src(user)   5=fol_dst(user)
    hipMemsetAsync(deg, 0, 6 * NP * sizeof(int), stream);
    deg_kernel<<<1024, 256, 0, stream>>>(rates_src, rates_dst, deg + 0 * NP, deg + 1 * NP, E0);
    deg_kernel<<<1024, 256, 0, stream>>>(rated_src, rated_dst, deg + 2 * NP, deg + 3 * NP, E1);
    deg_kernel<<<1024, 256, 0, stream>>>(fol_src,   fol_dst,   deg + 4 * NP, deg + 5 * NP, E2);
    inv_kernel<<<1024, 256, 0, stream>>>(deg, inv, (int)(6 * NP));

    // weight transposes (bf16 [N][K]); concat rates|fol for user-side GEMMs
    wt_kernel<<<(256 * 256 + 255) / 256, 256, 0, stream>>>(Wt1u, W1_rates, W1_fol, 256, 128, 128);
    wt_kernel<<<(128 * 128 + 255) / 256, 256, 0, stream>>>(Wt1i, W1_rated, W1_rated, 128, 128, 0);
    wt_kernel<<<(128 * 128 + 255) / 256, 256, 0, stream>>>(Wt2u, W2_rates, W2_fol, 128, 64, 64);
    wt_kernel<<<(128 * 64 + 255) / 256, 256, 0, stream>>>(Wt2i, W2_rated, W2_rated, 128, 64, 0);

    // ---- CSR build (by destination) ----
    const int nblk = (int)(NP / 1024);
    scan_part<<<dim3(nblk, 3), 256, 0, stream>>>(
        deg + 1 * NP, deg + 3 * NP, deg + 5 * NP, n_item, n_user, n_user, partial, nblk);
    scan_mid<<<3, 128, 0, stream>>>(partial, nblk);
    scan_final<<<dim3(nblk, 3), 256, 0, stream>>>(
        deg + 1 * NP, deg + 3 * NP, deg + 5 * NP, n_item, n_user, n_user, partial,
        cursor + 0 * NP, cursor + 1 * NP, cursor + 2 * NP, nblk);
    csr_fill<<<2048, 256, 0, stream>>>(rates_src, rates_dst, cursor + 0 * NP, csr0, E0);
    csr_fill<<<2048, 256, 0, stream>>>(rated_src, rated_dst, cursor + 1 * NP, csr1, E1);
    csr_fill<<<2048, 256, 0, stream>>>(fol_src,   fol_dst,   cursor + 2 * NP, csr2, E2);

    const int gbU = (n_user + 127) / 128;
    const int gbI = (n_item + 127) / 128;
    const int gwU = (n_user * 64 + 255) / 256;
    const int gwI = (n_item * 64 + 255) / 256;

    // ---- layer 1 GEMMs (fused user: rates|fol -> t1u[.,0:128 | 128:256]) --
    gemm_mfma<256, 128, false><<<dim3(gbU, 2), 256, 0, stream>>>(
        feat_user, Wt1u, inv + 0 * NP, inv + 4 * NP, 128, t1u, n_user, 256);
    gemm_mfma<128, 128, false><<<dim3(gbI, 1), 256, 0, stream>>>(
        feat_item, Wt1i, inv + 2 * NP, inv + 2 * NP, 1 << 30, t1i, n_item, 128);

    // ---- layer 1 gathers (write bf16 agg; bias+relu fused) ----
    gather<128, false, true, true><<<gwI, 256, 0, stream>>>(
        t1u, 256, 0, csr0, cursor + 0 * NP, deg + 1 * NP, inv + 1 * NP, b1_rates,
        nullptr, 0, 0, nullptr, nullptr, nullptr, nullptr, nullptr,
        aggI, n_item);
    gather<128, true, true, true><<<gwU, 256, 0, stream>>>(
        t1i, 128, 0, csr1, cursor + 1 * NP, deg + 3 * NP, inv + 3 * NP, b1_rated,
        t1u, 256, 128, csr2, cursor + 2 * NP, deg + 5 * NP, inv + 5 * NP, b1_fol,
        aggU, n_user);

    // ---- layer 2 GEMMs (A = bf16 agg) ----
    gemm_mfma<128, 128, true><<<dim3(gbU, 1), 256, 0, stream>>>(
        aggU, Wt2u, inv + 0 * NP, inv + 4 * NP, 64, t2u, n_user, 128);
    gemm_mfma<128, 64, true><<<dim3(gbI, 1), 128, 0, stream>>>(
        aggI, Wt2i, inv + 2 * NP, inv + 2 * NP, 1 << 30, t2i, n_item, 64);

    // ---- layer 2 gathers (straight into d_out, fp32) ----
    gather<64, false, false, false><<<gwI, 256, 0, stream>>>(
        t2u, 128, 0, csr0, cursor + 0 * NP, deg + 1 * NP, inv + 1 * NP, b2_rates,
        nullptr, 0, 0, nullptr, nullptr, nullptr, nullptr, nullptr,
        o_item, n_item);
    gather<64, true, false, false><<<gwU, 256, 0, stream>>>(
        t2i, 64, 0, csr1, cursor + 1 * NP, deg + 3 * NP, inv + 3 * NP, b2_rated,
        t2u, 128, 64, csr2, cursor + 2 * NP, deg + 5 * NP, inv + 5 * NP, b2_fol,
        o_user, n_user);
}

// Round 5
// 847.397 us; speedup vs baseline: 7.8556x; 1.1859x over previous
//
#include <hip/hip_runtime.h>
#include <math.h>

#define IN_USER 256
#define IN_ITEM 128
#define HID 128
#define OUTF 64

typedef unsigned short u16;
typedef unsigned int u32;
typedef __attribute__((ext_vector_type(8))) __bf16 bf16x8;
typedef __attribute__((ext_vector_type(4))) float f32x4;

__device__ __forceinline__ u16 f2bf(float f) {
    union { float f; u32 u; } c; c.f = f;
    return (u16)((c.u + 0x7fffu + ((c.u >> 16) & 1u)) >> 16);
}
__device__ __forceinline__ float bf2f(u16 h) {
    union { u32 u; float f; } c; c.u = ((u32)h) << 16;
    return c.f;
}
__device__ __forceinline__ u32 pack2(float a, float b) {
    return (u32)f2bf(a) | ((u32)f2bf(b) << 16);
}

// ---------------- degree histogram (3 relations in one launch) ----------
__global__ __launch_bounds__(256) void deg3_kernel(
        const int* __restrict__ s0, const int* __restrict__ d0, int e0,
        const int* __restrict__ s1, const int* __restrict__ d1, int e1,
        const int* __restrict__ s2, const int* __restrict__ d2, int e2,
        int* __restrict__ deg, int NP) {
    const int rel = blockIdx.y;
    const int* src = rel == 0 ? s0 : (rel == 1 ? s1 : s2);
    const int* dst = rel == 0 ? d0 : (rel == 1 ? d1 : d2);
    const int E = rel == 0 ? e0 : (rel == 1 ? e1 : e2);
    int* degs = deg + (2 * rel) * NP;
    int* degd = deg + (2 * rel + 1) * NP;
    const int stride = gridDim.x * blockDim.x;
    for (int i = blockIdx.x * blockDim.x + threadIdx.x; i < E; i += stride) {
        atomicAdd(&degs[src[i]], 1);
        atomicAdd(&degd[dst[i]], 1);
    }
}

__global__ __launch_bounds__(256) void inv_kernel(
        const int* __restrict__ deg, float* __restrict__ inv, int n) {
    const int stride = gridDim.x * blockDim.x;
    for (int i = blockIdx.x * blockDim.x + threadIdx.x; i < n; i += stride) {
        const int d = deg[i];
        inv[i] = 1.0f / sqrtf((float)(d > 1 ? d : 1));
    }
}

// ---------------- device-wide exclusive scan (3 relations batched) ------
__global__ __launch_bounds__(256) void scan_part(
        const int* __restrict__ d0, const int* __restrict__ d1,
        const int* __restrict__ d2, int n0, int n1, int n2,
        int* __restrict__ partial, int nblk) {
    const int rel = blockIdx.y;
    const int* deg = rel == 0 ? d0 : (rel == 1 ? d1 : d2);
    const int n = rel == 0 ? n0 : (rel == 1 ? n1 : n2);
    const int base = blockIdx.x * 1024 + threadIdx.x * 4;
    int s = 0;
#pragma unroll
    for (int i = 0; i < 4; ++i) {
        const int idx = base + i;
        if (idx < n) s += deg[idx];
    }
    __shared__ int red[256];
    red[threadIdx.x] = s;
    __syncthreads();
#pragma unroll
    for (int off = 128; off > 0; off >>= 1) {
        if (threadIdx.x < off) red[threadIdx.x] += red[threadIdx.x + off];
        __syncthreads();
    }
    if (threadIdx.x == 0) partial[rel * nblk + blockIdx.x] = red[0];
}

__global__ __launch_bounds__(128) void scan_mid(int* __restrict__ partial, int nblk) {
    __shared__ int sc[128];
    const int rel = blockIdx.x;
    const int t = threadIdx.x;
    const int v = (t < nblk) ? partial[rel * nblk + t] : 0;
    sc[t] = v;
    __syncthreads();
    for (int off = 1; off < 128; off <<= 1) {
        const int u = (t >= off) ? sc[t - off] : 0;
        __syncthreads();
        sc[t] += u;
        __syncthreads();
    }
    if (t < nblk) partial[rel * nblk + t] = sc[t] - v;
}

__global__ __launch_bounds__(256) void scan_final(
        const int* __restrict__ d0, const int* __restrict__ d1,
        const int* __restrict__ d2, int n0, int n1, int n2,
        const int* __restrict__ partial,
        int* __restrict__ c0, int* __restrict__ c1, int* __restrict__ c2,
        int nblk) {
    const int rel = blockIdx.y;
    const int* deg = rel == 0 ? d0 : (rel == 1 ? d1 : d2);
    int* cur = rel == 0 ? c0 : (rel == 1 ? c1 : c2);
    const int n = rel == 0 ? n0 : (rel == 1 ? n1 : n2);
    const int base = blockIdx.x * 1024 + threadIdx.x * 4;
    int v[4];
    int s = 0;
#pragma unroll
    for (int i = 0; i < 4; ++i) {
        const int idx = base + i;
        v[i] = (idx < n) ? deg[idx] : 0;
        s += v[i];
    }
    __shared__ int sc[256];
    sc[threadIdx.x] = s;
    __syncthreads();
    for (int off = 1; off < 256; off <<= 1) {
        const int u = (threadIdx.x >= off) ? sc[threadIdx.x - off] : 0;
        __syncthreads();
        sc[threadIdx.x] += u;
        __syncthreads();
    }
    int run = (threadIdx.x == 0 ? 0 : sc[threadIdx.x - 1]) + partial[rel * nblk + blockIdx.x];
#pragma unroll
    for (int i = 0; i < 4; ++i) {
        const int idx = base + i;
        if (idx < n) cur[idx] = run;
        run += v[i];
    }
}

// ------------- CSR fill (3 relations in one launch) -------------
__global__ __launch_bounds__(256) void csr_fill3(
        const int* __restrict__ s0, const int* __restrict__ d0, int e0,
        const int* __restrict__ s1, const int* __restrict__ d1, int e1,
        const int* __restrict__ s2, const int* __restrict__ d2, int e2,
        int* __restrict__ cursor, int NP,
        int* __restrict__ csrbase, int off1, int off2) {
    const int rel = blockIdx.y;
    const int* src = rel == 0 ? s0 : (rel == 1 ? s1 : s2);
    const int* dst = rel == 0 ? d0 : (rel == 1 ? d1 : d2);
    const int E = rel == 0 ? e0 : (rel == 1 ? e1 : e2);
    int* cur = cursor + rel * NP;
    int* csr = csrbase + (rel == 0 ? 0 : (rel == 1 ? off1 : off2));
    const int stride = gridDim.x * blockDim.x;
    for (int i = blockIdx.x * blockDim.x + threadIdx.x; i < E; i += stride) {
        const int pos = atomicAdd(&cur[dst[i]], 1);
        csr[pos] = src[i];
    }
}

// -------- weight transpose + concat: dst[n][k] (bf16) from src[k][n] fp32 --
__global__ __launch_bounds__(256) void wt_kernel(
        u16* __restrict__ dst, const float* __restrict__ s0,
        const float* __restrict__ s1, int K, int N0, int N1) {
    const int i = blockIdx.x * 256 + threadIdx.x;
    const int tot = K * (N0 + N1);
    if (i >= tot) return;
    const int n = i / K, k = i - n * K;
    const float v = (n < N0) ? s0[k * N0 + n] : s1[k * N1 + (n - N0)];
    dst[(size_t)n * K + k] = f2bf(v);
}

// -------- MFMA GEMM: T = bf16((X @ Wt^T) * inv[:,None]) --------
template<int K, int BN, bool A_BF16>
__global__ __launch_bounds__(BN * 2) void gemm_mfma(
        const void* __restrict__ Xv, const u16* __restrict__ Wt,
        const float* __restrict__ invA, const float* __restrict__ invB,
        int nsplit, u16* __restrict__ T, int M, int TN) {
    constexpr int BLK = BN * 2;
    constexpr int WN = BN / 64;
    constexpr int CA = 1024 / BLK;
    constexpr int CB = (BN * 8) / BLK;
    __shared__ u16 lA[128 * 64];
    __shared__ u16 lB[BN * 64];

    const int tid = threadIdx.x;
    const int row0 = blockIdx.x * 128;
    const int col0 = blockIdx.y * BN;
    const int wid = tid >> 6, lane = tid & 63;
    const int wm = wid / WN, wn = wid % WN;
    const int l15 = lane & 15, lhi = lane >> 4;

    f32x4 acc[4][4] = {};

    for (int kk = 0; kk < K; kk += 64) {
        __syncthreads();
#pragma unroll
        for (int c = 0; c < CA; ++c) {
            const int cid = tid + c * BLK;
            const int row = cid >> 3, kc = cid & 7;
            const int grow = row0 + row;
            uint4 u = make_uint4(0, 0, 0, 0);
            if (A_BF16) {
                if (grow < M)
                    u = *reinterpret_cast<const uint4*>(
                        (const u16*)Xv + (size_t)grow * K + kk + kc * 8);
            } else {
                if (grow < M) {
                    const float* xp = (const float*)Xv + (size_t)grow * K + kk + kc * 8;
                    const float4 v0 = *reinterpret_cast<const float4*>(xp);
                    const float4 v1 = *reinterpret_cast<const float4*>(xp + 4);
                    u.x = pack2(v0.x, v0.y); u.y = pack2(v0.z, v0.w);
                    u.z = pack2(v1.x, v1.y); u.w = pack2(v1.z, v1.w);
                }
            }
            const int e = row * 64 + ((kc ^ (row & 7)) << 3);
            *reinterpret_cast<uint4*>(&lA[e]) = u;
        }
#pragma unroll
        for (int c = 0; c < CB; ++c) {
            const int cid = tid + c * BLK;
            const int n = cid >> 3, kc = cid & 7;
            const uint4 u = *reinterpret_cast<const uint4*>(
                Wt + (size_t)(col0 + n) * K + kk + kc * 8);
            const int e = n * 64 + ((kc ^ (n & 7)) << 3);
            *reinterpret_cast<uint4*>(&lB[e]) = u;
        }
        __syncthreads();
#pragma unroll
        for (int ks = 0; ks < 2; ++ks) {
            const int cb = ks * 4 + lhi;
            bf16x8 af[4], bfr[4];
#pragma unroll
            for (int fm = 0; fm < 4; ++fm) {
                const int r = wm * 64 + fm * 16 + l15;
                const uint4 u = *reinterpret_cast<const uint4*>(
                    &lA[r * 64 + ((cb ^ (r & 7)) << 3)]);
                af[fm] = __builtin_bit_cast(bf16x8, u);
            }
#pragma unroll
            for (int fn = 0; fn < 4; ++fn) {
                const int r = wn * 64 + fn * 16 + l15;
                const uint4 u = *reinterpret_cast<const uint4*>(
                    &lB[r * 64 + ((cb ^ (r & 7)) << 3)]);
                bfr[fn] = __builtin_bit_cast(bf16x8, u);
            }
#pragma unroll
            for (int fm = 0; fm < 4; ++fm)
#pragma unroll
                for (int fn = 0; fn < 4; ++fn)
                    acc[fm][fn] = __builtin_amdgcn_mfma_f32_16x16x32_bf16(
                        af[fm], bfr[fn], acc[fm][fn], 0, 0, 0);
        }
    }

    const int colw = col0 + wn * 64;
    const float* invp = (colw >= nsplit) ? invB : invA;
#pragma unroll
    for (int fm = 0; fm < 4; ++fm) {
#pragma unroll
        for (int r4 = 0; r4 < 4; ++r4) {
            const int grow = row0 + wm * 64 + fm * 16 + lhi * 4 + r4;
            if (grow < M) {
                const float s = invp[grow];
#pragma unroll
                for (int fn = 0; fn < 4; ++fn) {
                    const int col = colw + fn * 16 + l15;
                    T[(size_t)grow * TN + col] = f2bf(acc[fm][fn][r4] * s);
                }
            }
        }
    }
}

// -------- pull-aggregation over bf16 T, one wave per dst node -----------
// Edge loop software-pipelined in batches of 8: 8 independent index loads,
// then 8 independent row loads in flight, then accumulate (breaks the
// idx->row->idx dependency chain; MLP 1 -> 8).
template<int F>
__device__ __forceinline__ void gather_rel(
        const u16* __restrict__ T, int strideT, int offT,
        const int* __restrict__ csr, int beg, int cnt, int lane,
        float& s0, float& s1) {
    const int* cp = csr + beg;
    int e = 0;
    for (; e + 8 <= cnt; e += 8) {
        int idx[8];
#pragma unroll
        for (int i = 0; i < 8; ++i) idx[i] = cp[e + i];
        if (F == 128) {
            u32 v[8];
#pragma unroll
            for (int i = 0; i < 8; ++i)
                v[i] = *reinterpret_cast<const u32*>(
                    T + (size_t)idx[i] * strideT + offT + lane * 2);
#pragma unroll
            for (int i = 0; i < 8; ++i) {
                s0 += bf2f((u16)v[i]); s1 += bf2f((u16)(v[i] >> 16));
            }
        } else {
            u16 v[8];
#pragma unroll
            for (int i = 0; i < 8; ++i)
                v[i] = T[(size_t)idx[i] * strideT + offT + lane];
#pragma unroll
            for (int i = 0; i < 8; ++i) s0 += bf2f(v[i]);
        }
    }
    for (; e < cnt; ++e) {
        const int s = cp[e];
        if (F == 128) {
            const u32 v = *reinterpret_cast<const u32*>(
                T + (size_t)s * strideT + offT + lane * 2);
            s0 += bf2f((u16)v); s1 += bf2f((u16)(v >> 16));
        } else {
            s0 += bf2f(T[(size_t)s * strideT + offT + lane]);
        }
    }
}

template<int F, bool TWO, bool RELU, bool BF16OUT>
__global__ __launch_bounds__(256) void gather(
        const u16* __restrict__ Ta, int strideA, int offA,
        const int* __restrict__ csrA, const int* __restrict__ curA,
        const int* __restrict__ degA, const float* __restrict__ invA,
        const float* __restrict__ biasA,
        const u16* __restrict__ Tb, int strideB, int offB,
        const int* __restrict__ csrB, const int* __restrict__ curB,
        const int* __restrict__ degB, const float* __restrict__ invB,
        const float* __restrict__ biasB,
        void* __restrict__ outv, int n) {
    const int wid = (blockIdx.x * 256 + threadIdx.x) >> 6;
    const int lane = threadIdx.x & 63;
    if (wid >= n) return;
    float r0, r1 = 0.f;
    {
        const int cnt = degA[wid];
        const int beg = curA[wid] - cnt;
        float s0 = 0.f, s1 = 0.f;
        gather_rel<F>(Ta, strideA, offA, csrA, beg, cnt, lane, s0, s1);
        const float a = invA[wid];
        if (F == 128) {
            const float2 b = *reinterpret_cast<const float2*>(biasA + lane * 2);
            r0 = s0 * a + b.x; r1 = s1 * a + b.y;
        } else {
            r0 = s0 * a + biasA[lane];
        }
    }
    if (TWO) {
        const int cnt = degB[wid];
        const int beg = curB[wid] - cnt;
        float s0 = 0.f, s1 = 0.f;
        gather_rel<F>(Tb, strideB, offB, csrB, beg, cnt, lane, s0, s1);
        const float a = invB[wid];
        if (F == 128) {
            const float2 b = *reinterpret_cast<const float2*>(biasB + lane * 2);
            r0 += s0 * a + b.x; r1 += s1 * a + b.y;
        } else {
            r0 += s0 * a + biasB[lane];
        }
    }
    if (RELU) { r0 = fmaxf(r0, 0.f); r1 = fmaxf(r1, 0.f); }
    if (BF16OUT) {
        if (F == 128)
            ((u32*)outv)[(size_t)wid * 64 + lane] = pack2(r0, r1);
        else
            ((u16*)outv)[(size_t)wid * 64 + lane] = f2bf(r0);
    } else {
        if (F == 128) {
            float2 o; o.x = r0; o.y = r1;
            *reinterpret_cast<float2*>((float*)outv + (size_t)wid * 128 + lane * 2) = o;
        } else {
            ((float*)outv)[(size_t)wid * 64 + lane] = r0;
        }
    }
}

extern "C" void kernel_launch(void* const* d_in, const int* in_sizes, int n_in,
                              void* d_out, int out_size, void* d_ws, size_t ws_size,
                              hipStream_t stream) {
    const float* feat_user = (const float*)d_in[0];
    const float* feat_item = (const float*)d_in[1];
    const int* rates_src = (const int*)d_in[2];
    const int* rates_dst = (const int*)d_in[3];
    const int* rated_src = (const int*)d_in[4];
    const int* rated_dst = (const int*)d_in[5];
    const int* fol_src   = (const int*)d_in[6];
    const int* fol_dst   = (const int*)d_in[7];
    const float* W1_rates = (const float*)d_in[8];
    const float* b1_rates = (const float*)d_in[9];
    const float* W1_rated = (const float*)d_in[10];
    const float* b1_rated = (const float*)d_in[11];
    const float* W1_fol   = (const float*)d_in[12];
    const float* b1_fol   = (const float*)d_in[13];
    const float* W2_rates = (const float*)d_in[14];
    const float* b2_rates = (const float*)d_in[15];
    const float* W2_rated = (const float*)d_in[16];
    const float* b2_rated = (const float*)d_in[17];
    const float* W2_fol   = (const float*)d_in[18];
    const float* b2_fol   = (const float*)d_in[19];

    const int n_user = in_sizes[0] / IN_USER;
    const int n_item = in_sizes[1] / IN_ITEM;
    const int E0 = in_sizes[2];
    const int E1 = in_sizes[4];
    const int E2 = in_sizes[6];
    const int nmax = n_user > n_item ? n_user : n_item;

    // ---- workspace layout ----
    const size_t NP = ((size_t)(nmax + 1023) / 1024) * 1024;
    int*   deg     = (int*)d_ws;                   // [6][NP]
    float* inv     = (float*)(deg + 6 * NP);       // [6][NP]
    int*   cursor  = (int*)(inv + 6 * NP);         // [3][NP]
    int*   partial = cursor + 3 * NP;              // [3][128]
    int*   csr     = partial + 3 * 128;
    int*   csr0 = csr;
    int*   csr1 = csr + E0;
    int*   csr2 = csr + E0 + E1;
    u16* Wt1u = (u16*)(csr + E0 + E1 + E2);        // [256][256]
    u16* Wt1i = Wt1u + 256 * 256;                  // [128][128]
    u16* Wt2u = Wt1i + 128 * 128;                  // [128][128]
    u16* Wt2i = Wt2u + 128 * 128;                  // [64][128]
    u16* t1u  = Wt2i + 64 * 128;                   // [nmax][256] bf16
    u16* t1i  = t1u + (size_t)nmax * 256;          // [nmax][128] bf16
    u16* aggU = t1i + (size_t)nmax * 128;          // [n_user][128] bf16
    u16* aggI = aggU + (size_t)nmax * 128;         // [n_item][128] bf16
    u16* t2u  = t1i;   // alias: t1i dead after user_L1 gather
    u16* t2i  = t1u;   // alias: t1u dead after user_L1 gather

    float* o_user = (float*)d_out;
    float* o_item = o_user + (size_t)n_user * OUTF;

    // deg idx: 0=rates_src(user) 1=rates_dst(item) 2=rated_src(item)
    //          3=rated_dst(user) 4=fol_src(user)   5=fol_dst(user)
    hipMemsetAsync(deg, 0, 6 * NP * sizeof(int), stream);
    deg3_kernel<<<dim3(512, 3), 256, 0, stream>>>(
        rates_src, rates_dst, E0, rated_src, rated_dst, E1,
        fol_src, fol_dst, E2, deg, (int)NP);
    inv_kernel<<<1024, 256, 0, stream>>>(deg, inv, (int)(6 * NP));

    wt_kernel<<<(256 * 256 + 255) / 256, 256, 0, stream>>>(Wt1u, W1_rates, W1_fol, 256, 128, 128);
    wt_kernel<<<(128 * 128 + 255) / 256, 256, 0, stream>>>(Wt1i, W1_rated, W1_rated, 128, 128, 0);
    wt_kernel<<<(128 * 128 + 255) / 256, 256, 0, stream>>>(Wt2u, W2_rates, W2_fol, 128, 64, 64);
    wt_kernel<<<(128 * 64 + 255) / 256, 256, 0, stream>>>(Wt2i, W2_rated, W2_rated, 128, 64, 0);

    const int nblk = (int)(NP / 1024);
    scan_part<<<dim3(nblk, 3), 256, 0, stream>>>(
        deg + 1 * NP, deg + 3 * NP, deg + 5 * NP, n_item, n_user, n_user, partial, nblk);
    scan_mid<<<3, 128, 0, stream>>>(partial, nblk);
    scan_final<<<dim3(nblk, 3), 256, 0, stream>>>(
        deg + 1 * NP, deg + 3 * NP, deg + 5 * NP, n_item, n_user, n_user, partial,
        cursor + 0 * NP, cursor + 1 * NP, cursor + 2 * NP, nblk);
    csr_fill3<<<dim3(1024, 3), 256, 0, stream>>>(
        rates_src, rates_dst, E0, rated_src, rated_dst, E1,
        fol_src, fol_dst, E2, cursor, (int)NP, csr, E0, E0 + E1);

    const int gbU = (n_user + 127) / 128;
    const int gbI = (n_item + 127) / 128;
    const int gwU = (n_user * 64 + 255) / 256;
    const int gwI = (n_item * 64 + 255) / 256;

    // ---- layer 1 GEMMs (fused user: rates|fol -> t1u[.,0:128 | 128:256]) --
    gemm_mfma<256, 128, false><<<dim3(gbU, 2), 256, 0, stream>>>(
        feat_user, Wt1u, inv + 0 * NP, inv + 4 * NP, 128, t1u, n_user, 256);
    gemm_mfma<128, 128, false><<<dim3(gbI, 1), 256, 0, stream>>>(
        feat_item, Wt1i, inv + 2 * NP, inv + 2 * NP, 1 << 30, t1i, n_item, 128);

    // ---- layer 1 gathers ----
    gather<128, false, true, true><<<gwI, 256, 0, stream>>>(
        t1u, 256, 0, csr0, cursor + 0 * NP, deg + 1 * NP, inv + 1 * NP, b1_rates,
        nullptr, 0, 0, nullptr, nullptr, nullptr, nullptr, nullptr,
        aggI, n_item);
    gather<128, true, true, true><<<gwU, 256, 0, stream>>>(
        t1i, 128, 0, csr1, cursor + 1 * NP, deg + 3 * NP, inv + 3 * NP, b1_rated,
        t1u, 256, 128, csr2, cursor + 2 * NP, deg + 5 * NP, inv + 5 * NP, b1_fol,
        aggU, n_user);

    // ---- layer 2 GEMMs ----
    gemm_mfma<128, 128, true><<<dim3(gbU, 1), 256, 0, stream>>>(
        aggU, Wt2u, inv + 0 * NP, inv + 4 * NP, 64, t2u, n_user, 128);
    gemm_mfma<128, 64, true><<<dim3(gbI, 1), 128, 0, stream>>>(
        aggI, Wt2i, inv + 2 * NP, inv + 2 * NP, 1 << 30, t2i, n_item, 64);

    // ---- layer 2 gathers (straight into d_out, fp32) ----
    gather<64, false, false, false><<<gwI, 256, 0, stream>>>(
        t2u, 128, 0, csr0, cursor + 0 * NP, deg + 1 * NP, inv + 1 * NP, b2_rates,
        nullptr, 0, 0, nullptr, nullptr, nullptr, nullptr, nullptr,
        o_item, n_item);
    gather<64, true, false, false><<<gwU, 256, 0, stream>>>(
        t2i, 64, 0, csr1, cursor + 1 * NP, deg + 3 * NP, inv + 3 * NP, b2_rated,
        t2u, 128, 64, csr2, cursor + 2 * NP, deg + 5 * NP, inv + 5 * NP, b2_fol,
        o_user, n_user);
}

// Round 6
// 682.838 us; speedup vs baseline: 9.7488x; 1.2410x over previous
//
#include <hip/hip_runtime.h>
#include <math.h>

#define IN_USER 256
#define IN_ITEM 128
#define HID 128
#define OUTF 64

typedef unsigned short u16;
typedef unsigned int u32;
typedef __attribute__((ext_vector_type(8))) __bf16 bf16x8;
typedef __attribute__((ext_vector_type(4))) float f32x4;

__device__ __forceinline__ u16 f2bf(float f) {
    union { float f; u32 u; } c; c.f = f;
    return (u16)((c.u + 0x7fffu + ((c.u >> 16) & 1u)) >> 16);
}
__device__ __forceinline__ float bf2f(u16 h) {
    union { u32 u; float f; } c; c.u = ((u32)h) << 16;
    return c.f;
}
__device__ __forceinline__ u32 pack2(float a, float b) {
    return (u32)f2bf(a) | ((u32)f2bf(b) << 16);
}
__device__ __host__ __forceinline__ int pad8(int x) { return (x + 7) & ~7; }

// ---------------- degree histogram (3 relations in one launch) ----------
__global__ __launch_bounds__(256) void deg3_kernel(
        const int* __restrict__ s0, const int* __restrict__ d0, int e0,
        const int* __restrict__ s1, const int* __restrict__ d1, int e1,
        const int* __restrict__ s2, const int* __restrict__ d2, int e2,
        int* __restrict__ deg, int NP) {
    const int rel = blockIdx.y;
    const int* src = rel == 0 ? s0 : (rel == 1 ? s1 : s2);
    const int* dst = rel == 0 ? d0 : (rel == 1 ? d1 : d2);
    const int E = rel == 0 ? e0 : (rel == 1 ? e1 : e2);
    int* degs = deg + (2 * rel) * NP;
    int* degd = deg + (2 * rel + 1) * NP;
    const int stride = gridDim.x * blockDim.x;
    for (int i = blockIdx.x * blockDim.x + threadIdx.x; i < E; i += stride) {
        atomicAdd(&degs[src[i]], 1);
        atomicAdd(&degd[dst[i]], 1);
    }
}

__global__ __launch_bounds__(256) void inv_kernel(
        const int* __restrict__ deg, float* __restrict__ inv, int n) {
    const int stride = gridDim.x * blockDim.x;
    for (int i = blockIdx.x * blockDim.x + threadIdx.x; i < n; i += stride) {
        const int d = deg[i];
        inv[i] = 1.0f / sqrtf((float)(d > 1 ? d : 1));
    }
}

// ------- exclusive scan over PADDED dst-degrees (3 relations batched) ----
__global__ __launch_bounds__(256) void scan_part(
        const int* __restrict__ d0, const int* __restrict__ d1,
        const int* __restrict__ d2, int n0, int n1, int n2,
        int* __restrict__ partial, int nblk) {
    const int rel = blockIdx.y;
    const int* deg = rel == 0 ? d0 : (rel == 1 ? d1 : d2);
    const int n = rel == 0 ? n0 : (rel == 1 ? n1 : n2);
    const int base = blockIdx.x * 1024 + threadIdx.x * 4;
    int s = 0;
#pragma unroll
    for (int i = 0; i < 4; ++i) {
        const int idx = base + i;
        if (idx < n) s += pad8(deg[idx]);
    }
    __shared__ int red[256];
    red[threadIdx.x] = s;
    __syncthreads();
#pragma unroll
    for (int off = 128; off > 0; off >>= 1) {
        if (threadIdx.x < off) red[threadIdx.x] += red[threadIdx.x + off];
        __syncthreads();
    }
    if (threadIdx.x == 0) partial[rel * nblk + blockIdx.x] = red[0];
}

__global__ __launch_bounds__(128) void scan_mid(int* __restrict__ partial, int nblk) {
    __shared__ int sc[128];
    const int rel = blockIdx.x;
    const int t = threadIdx.x;
    const int v = (t < nblk) ? partial[rel * nblk + t] : 0;
    sc[t] = v;
    __syncthreads();
    for (int off = 1; off < 128; off <<= 1) {
        const int u = (t >= off) ? sc[t - off] : 0;
        __syncthreads();
        sc[t] += u;
        __syncthreads();
    }
    if (t < nblk) partial[rel * nblk + t] = sc[t] - v;
}

__global__ __launch_bounds__(256) void scan_final(
        const int* __restrict__ d0, const int* __restrict__ d1,
        const int* __restrict__ d2, int n0, int n1, int n2,
        const int* __restrict__ partial,
        int* __restrict__ c0, int* __restrict__ c1, int* __restrict__ c2,
        int nblk) {
    const int rel = blockIdx.y;
    const int* deg = rel == 0 ? d0 : (rel == 1 ? d1 : d2);
    int* cur = rel == 0 ? c0 : (rel == 1 ? c1 : c2);
    const int n = rel == 0 ? n0 : (rel == 1 ? n1 : n2);
    const int base = blockIdx.x * 1024 + threadIdx.x * 4;
    int v[4];
    int s = 0;
#pragma unroll
    for (int i = 0; i < 4; ++i) {
        const int idx = base + i;
        v[i] = (idx < n) ? pad8(deg[idx]) : 0;
        s += v[i];
    }
    __shared__ int sc[256];
    sc[threadIdx.x] = s;
    __syncthreads();
    for (int off = 1; off < 256; off <<= 1) {
        const int u = (threadIdx.x >= off) ? sc[threadIdx.x - off] : 0;
        __syncthreads();
        sc[threadIdx.x] += u;
        __syncthreads();
    }
    int run = (threadIdx.x == 0 ? 0 : sc[threadIdx.x - 1]) + partial[rel * nblk + blockIdx.x];
#pragma unroll
    for (int i = 0; i < 4; ++i) {
        const int idx = base + i;
        if (idx < n) cur[idx] = run;
        run += v[i];
    }
}

// ------------- prefill csr with the zero-row index Z -------------
__global__ __launch_bounds__(256) void fillz_kernel(
        int* __restrict__ p, int z, int n) {
    const int stride = gridDim.x * blockDim.x;
    for (int i = blockIdx.x * blockDim.x + threadIdx.x; i < n; i += stride)
        p[i] = z;
}

// ------- CSR fill, dst-range partitioned (range = blockIdx.x & 7) -------
// Each XCD's L2 exclusively owns one ~RB-node slice of csr -> dense
// full-line writebacks instead of 17x-amplified random 4B scatter.
__global__ __launch_bounds__(256) void csr_fill_ranges(
        const int* __restrict__ s0, const int* __restrict__ d0, int e0,
        const int* __restrict__ s1, const int* __restrict__ d1, int e1,
        const int* __restrict__ s2, const int* __restrict__ d2, int e2,
        int* __restrict__ cursor, int NP, int RB,
        int* __restrict__ csrbase, int off1, int off2) {
    const int rel = blockIdx.y;
    const int* src = rel == 0 ? s0 : (rel == 1 ? s1 : s2);
    const int* dst = rel == 0 ? d0 : (rel == 1 ? d1 : d2);
    const int E = rel == 0 ? e0 : (rel == 1 ? e1 : e2);
    int* cur = cursor + rel * NP;
    int* csr = csrbase + (rel == 0 ? 0 : (rel == 1 ? off1 : off2));
    const int rng = blockIdx.x & 7;
    const int lo = rng * RB, hi = lo + RB;
    const int nch = gridDim.x >> 3;
    const int ch = blockIdx.x >> 3;
    for (int i = ch * 256 + threadIdx.x; i < E; i += nch * 256) {
        const int d = dst[i];
        if (d >= lo && d < hi) {
            const int pos = atomicAdd(&cur[d], 1);
            csr[pos] = src[i];
        }
    }
}

// -------- weight transpose + concat: dst[n][k] (bf16) from src[k][n] fp32 --
__global__ __launch_bounds__(256) void wt_kernel(
        u16* __restrict__ dst, const float* __restrict__ s0,
        const float* __restrict__ s1, int K, int N0, int N1) {
    const int i = blockIdx.x * 256 + threadIdx.x;
    const int tot = K * (N0 + N1);
    if (i >= tot) return;
    const int n = i / K, k = i - n * K;
    const float v = (n < N0) ? s0[k * N0 + n] : s1[k * N1 + (n - N0)];
    dst[(size_t)n * K + k] = f2bf(v);
}

// -------- MFMA GEMM: T = bf16((X @ Wt^T) * inv[:,None]) --------
template<int K, int BN, bool A_BF16>
__global__ __launch_bounds__(BN * 2) void gemm_mfma(
        const void* __restrict__ Xv, const u16* __restrict__ Wt,
        const float* __restrict__ invA, const float* __restrict__ invB,
        int nsplit, u16* __restrict__ T, int M, int TN) {
    constexpr int BLK = BN * 2;
    constexpr int WN = BN / 64;
    constexpr int CA = 1024 / BLK;
    constexpr int CB = (BN * 8) / BLK;
    __shared__ u16 lA[128 * 64];
    __shared__ u16 lB[BN * 64];

    const int tid = threadIdx.x;
    const int row0 = blockIdx.x * 128;
    const int col0 = blockIdx.y * BN;
    const int wid = tid >> 6, lane = tid & 63;
    const int wm = wid / WN, wn = wid % WN;
    const int l15 = lane & 15, lhi = lane >> 4;

    f32x4 acc[4][4] = {};

    for (int kk = 0; kk < K; kk += 64) {
        __syncthreads();
#pragma unroll
        for (int c = 0; c < CA; ++c) {
            const int cid = tid + c * BLK;
            const int row = cid >> 3, kc = cid & 7;
            const int grow = row0 + row;
            uint4 u = make_uint4(0, 0, 0, 0);
            if (A_BF16) {
                if (grow < M)
                    u = *reinterpret_cast<const uint4*>(
                        (const u16*)Xv + (size_t)grow * K + kk + kc * 8);
            } else {
                if (grow < M) {
                    const float* xp = (const float*)Xv + (size_t)grow * K + kk + kc * 8;
                    const float4 v0 = *reinterpret_cast<const float4*>(xp);
                    const float4 v1 = *reinterpret_cast<const float4*>(xp + 4);
                    u.x = pack2(v0.x, v0.y); u.y = pack2(v0.z, v0.w);
                    u.z = pack2(v1.x, v1.y); u.w = pack2(v1.z, v1.w);
                }
            }
            const int e = row * 64 + ((kc ^ (row & 7)) << 3);
            *reinterpret_cast<uint4*>(&lA[e]) = u;
        }
#pragma unroll
        for (int c = 0; c < CB; ++c) {
            const int cid = tid + c * BLK;
            const int n = cid >> 3, kc = cid & 7;
            const uint4 u = *reinterpret_cast<const uint4*>(
                Wt + (size_t)(col0 + n) * K + kk + kc * 8);
            const int e = n * 64 + ((kc ^ (n & 7)) << 3);
            *reinterpret_cast<uint4*>(&lB[e]) = u;
        }
        __syncthreads();
#pragma unroll
        for (int ks = 0; ks < 2; ++ks) {
            const int cb = ks * 4 + lhi;
            bf16x8 af[4], bfr[4];
#pragma unroll
            for (int fm = 0; fm < 4; ++fm) {
                const int r = wm * 64 + fm * 16 + l15;
                const uint4 u = *reinterpret_cast<const uint4*>(
                    &lA[r * 64 + ((cb ^ (r & 7)) << 3)]);
                af[fm] = __builtin_bit_cast(bf16x8, u);
            }
#pragma unroll
            for (int fn = 0; fn < 4; ++fn) {
                const int r = wn * 64 + fn * 16 + l15;
                const uint4 u = *reinterpret_cast<const uint4*>(
                    &lB[r * 64 + ((cb ^ (r & 7)) << 3)]);
                bfr[fn] = __builtin_bit_cast(bf16x8, u);
            }
#pragma unroll
            for (int fm = 0; fm < 4; ++fm)
#pragma unroll
                for (int fn = 0; fn < 4; ++fn)
                    acc[fm][fn] = __builtin_amdgcn_mfma_f32_16x16x32_bf16(
                        af[fm], bfr[fn], acc[fm][fn], 0, 0, 0);
        }
    }

    const int colw = col0 + wn * 64;
    const float* invp = (colw >= nsplit) ? invB : invA;
#pragma unroll
    for (int fm = 0; fm < 4; ++fm) {
#pragma unroll
        for (int r4 = 0; r4 < 4; ++r4) {
            const int grow = row0 + wm * 64 + fm * 16 + lhi * 4 + r4;
            if (grow < M) {
                const float s = invp[grow];
#pragma unroll
                for (int fn = 0; fn < 4; ++fn) {
                    const int col = colw + fn * 16 + l15;
                    T[(size_t)grow * TN + col] = f2bf(acc[fm][fn][r4] * s);
                }
            }
        }
    }
}

// -------- pull-aggregation over bf16 T, one wave per dst node -----------
// CSR segments are padded to multiples of 8 with the zero-row index, so the
// edge loop is a uniform batch-8 pipeline: 8 independent index loads, 8
// independent row loads in flight, no serial remainder.
template<int F>
__device__ __forceinline__ void gather_rel(
        const u16* __restrict__ T, int strideT, int offT,
        const int* __restrict__ csr, int beg, int pcnt, int lane,
        float& s0, float& s1) {
    const int* cp = csr + beg;
    for (int e = 0; e < pcnt; e += 8) {
        int idx[8];
#pragma unroll
        for (int i = 0; i < 8; ++i) idx[i] = cp[e + i];
        if (F == 128) {
            u32 v[8];
#pragma unroll
            for (int i = 0; i < 8; ++i)
                v[i] = *reinterpret_cast<const u32*>(
                    T + (size_t)idx[i] * strideT + offT + lane * 2);
#pragma unroll
            for (int i = 0; i < 8; ++i) {
                s0 += bf2f((u16)v[i]); s1 += bf2f((u16)(v[i] >> 16));
            }
        } else {
            u16 v[8];
#pragma unroll
            for (int i = 0; i < 8; ++i)
                v[i] = T[(size_t)idx[i] * strideT + offT + lane];
#pragma unroll
            for (int i = 0; i < 8; ++i) s0 += bf2f(v[i]);
        }
    }
}

template<int F, bool TWO, bool RELU, bool BF16OUT>
__global__ __launch_bounds__(256) void gather(
        const u16* __restrict__ Ta, int strideA, int offA,
        const int* __restrict__ csrA, const int* __restrict__ curA,
        const int* __restrict__ degA, const float* __restrict__ invA,
        const float* __restrict__ biasA,
        const u16* __restrict__ Tb, int strideB, int offB,
        const int* __restrict__ csrB, const int* __restrict__ curB,
        const int* __restrict__ degB, const float* __restrict__ invB,
        const float* __restrict__ biasB,
        void* __restrict__ outv, int n) {
    const int wid = (blockIdx.x * 256 + threadIdx.x) >> 6;
    const int lane = threadIdx.x & 63;
    if (wid >= n) return;
    float r0, r1 = 0.f;
    {
        const int cnt = degA[wid];
        const int beg = curA[wid] - cnt;
        float s0 = 0.f, s1 = 0.f;
        gather_rel<F>(Ta, strideA, offA, csrA, beg, pad8(cnt), lane, s0, s1);
        const float a = invA[wid];
        if (F == 128) {
            const float2 b = *reinterpret_cast<const float2*>(biasA + lane * 2);
            r0 = s0 * a + b.x; r1 = s1 * a + b.y;
        } else {
            r0 = s0 * a + biasA[lane];
        }
    }
    if (TWO) {
        const int cnt = degB[wid];
        const int beg = curB[wid] - cnt;
        float s0 = 0.f, s1 = 0.f;
        gather_rel<F>(Tb, strideB, offB, csrB, beg, pad8(cnt), lane, s0, s1);
        const float a = invB[wid];
        if (F == 128) {
            const float2 b = *reinterpret_cast<const float2*>(biasB + lane * 2);
            r0 += s0 * a + b.x; r1 += s1 * a + b.y;
        } else {
            r0 += s0 * a + biasB[lane];
        }
    }
    if (RELU) { r0 = fmaxf(r0, 0.f); r1 = fmaxf(r1, 0.f); }
    if (BF16OUT) {
        if (F == 128)
            ((u32*)outv)[(size_t)wid * 64 + lane] = pack2(r0, r1);
        else
            ((u16*)outv)[(size_t)wid * 64 + lane] = f2bf(r0);
    } else {
        if (F == 128) {
            float2 o; o.x = r0; o.y = r1;
            *reinterpret_cast<float2*>((float*)outv + (size_t)wid * 128 + lane * 2) = o;
        } else {
            ((float*)outv)[(size_t)wid * 64 + lane] = r0;
        }
    }
}

extern "C" void kernel_launch(void* const* d_in, const int* in_sizes, int n_in,
                              void* d_out, int out_size, void* d_ws, size_t ws_size,
                              hipStream_t stream) {
    const float* feat_user = (const float*)d_in[0];
    const float* feat_item = (const float*)d_in[1];
    const int* rates_src = (const int*)d_in[2];
    const int* rates_dst = (const int*)d_in[3];
    const int* rated_src = (const int*)d_in[4];
    const int* rated_dst = (const int*)d_in[5];
    const int* fol_src   = (const int*)d_in[6];
    const int* fol_dst   = (const int*)d_in[7];
    const float* W1_rates = (const float*)d_in[8];
    const float* b1_rates = (const float*)d_in[9];
    const float* W1_rated = (const float*)d_in[10];
    const float* b1_rated = (const float*)d_in[11];
    const float* W1_fol   = (const float*)d_in[12];
    const float* b1_fol   = (const float*)d_in[13];
    const float* W2_rates = (const float*)d_in[14];
    const float* b2_rates = (const float*)d_in[15];
    const float* W2_rated = (const float*)d_in[16];
    const float* b2_rated = (const float*)d_in[17];
    const float* W2_fol   = (const float*)d_in[18];
    const float* b2_fol   = (const float*)d_in[19];

    const int n_user = in_sizes[0] / IN_USER;
    const int n_item = in_sizes[1] / IN_ITEM;
    const int E0 = in_sizes[2];
    const int E1 = in_sizes[4];
    const int E2 = in_sizes[6];
    const int nmax = n_user > n_item ? n_user : n_item;
    const int Z = nmax;   // zero-row index (padding target)

    // ---- workspace layout ----
    const size_t NP = ((size_t)(nmax + 1023) / 1024) * 1024;   // 100352
    int*   deg     = (int*)d_ws;                   // [6][NP]
    float* inv     = (float*)(deg + 6 * NP);       // [6][NP]
    int*   cursor  = (int*)(inv + 6 * NP);         // [3][NP]
    int*   partial = cursor + 3 * NP;              // [3][128]
    // padded CSR capacities (pad8 per node upper bound)
    const int cap0 = E0 + 8 * n_item;
    const int cap1 = E1 + 8 * n_user;
    const int cap2 = E2 + 8 * n_user;
    int*   csr  = partial + 3 * 128;
    int*   csr0 = csr;
    int*   csr1 = csr + cap0;
    int*   csr2 = csr + cap0 + cap1;
    u16* Wt1u = (u16*)(csr + cap0 + cap1 + cap2);  // [256][256]
    u16* Wt1i = Wt1u + 256 * 256;                  // [128][128]
    u16* Wt2u = Wt1i + 128 * 128;                  // [128][128]
    u16* Wt2i = Wt2u + 128 * 128;                  // [64][128]
    u16* t1u  = Wt2i + 64 * 128;                   // [nmax+1][256] bf16
    u16* t1i  = t1u + (size_t)(nmax + 1) * 256;    // [nmax+1][128] bf16
    u16* aggU = t1i + (size_t)(nmax + 1) * 128;    // [n_user][128] bf16
    u16* aggI = aggU + (size_t)nmax * 128;         // [n_item][128] bf16
    u16* t2u  = t1i;   // alias: t1i dead after user_L1 gather (stride 128 ==)
    u16* t2i  = t1u;   // alias: t1u dead after user_L1 gather (stride 64)

    float* o_user = (float*)d_out;
    float* o_item = o_user + (size_t)n_user * OUTF;

    // deg idx: 0=rates_src(user) 1=rates_dst(item) 2=rated_src(item)
    //          3=rated_dst(user) 4=fol_src(user)   5=fol_dst(user)
    hipMemsetAsync(deg, 0, 6 * NP * sizeof(int), stream);
    // zero rows for padded gathers (t2i's Z row re-zeroed later, its slot
    // overlaps live t1u data until the L1 gathers finish)
    hipMemsetAsync(t1u + (size_t)Z * 256, 0, 512, stream);
    hipMemsetAsync(t1i + (size_t)Z * 128, 0, 256, stream);   // == t2u Z row

    deg3_kernel<<<dim3(512, 3), 256, 0, stream>>>(
        rates_src, rates_dst, E0, rated_src, rated_dst, E1,
        fol_src, fol_dst, E2, deg, (int)NP);
    inv_kernel<<<1024, 256, 0, stream>>>(deg, inv, (int)(6 * NP));

    wt_kernel<<<(256 * 256 + 255) / 256, 256, 0, stream>>>(Wt1u, W1_rates, W1_fol, 256, 128, 128);
    wt_kernel<<<(128 * 128 + 255) / 256, 256, 0, stream>>>(Wt1i, W1_rated, W1_rated, 128, 128, 0);
    wt_kernel<<<(128 * 128 + 255) / 256, 256, 0, stream>>>(Wt2u, W2_rates, W2_fol, 128, 64, 64);
    wt_kernel<<<(128 * 64 + 255) / 256, 256, 0, stream>>>(Wt2i, W2_rated, W2_rated, 128, 64, 0);

    // ---- CSR build (by destination, padded segments) ----
    fillz_kernel<<<2048, 256, 0, stream>>>(csr, Z, cap0 + cap1 + cap2);
    const int nblk = (int)(NP / 1024);
    scan_part<<<dim3(nblk, 3), 256, 0, stream>>>(
        deg + 1 * NP, deg + 3 * NP, deg + 5 * NP, n_item, n_user, n_user, partial, nblk);
    scan_mid<<<3, 128, 0, stream>>>(partial, nblk);
    scan_final<<<dim3(nblk, 3), 256, 0, stream>>>(
        deg + 1 * NP, deg + 3 * NP, deg + 5 * NP, n_item, n_user, n_user, partial,
        cursor + 0 * NP, cursor + 1 * NP, cursor + 2 * NP, nblk);
    csr_fill_ranges<<<dim3(512, 3), 256, 0, stream>>>(
        rates_src, rates_dst, E0, rated_src, rated_dst, E1,
        fol_src, fol_dst, E2, cursor, (int)NP, (int)(NP / 8), csr, cap0, cap0 + cap1);

    const int gbU = (n_user + 127) / 128;
    const int gbI = (n_item + 127) / 128;
    const int gwU = (n_user * 64 + 255) / 256;
    const int gwI = (n_item * 64 + 255) / 256;

    // ---- layer 1 GEMMs (fused user: rates|fol -> t1u[.,0:128 | 128:256]) --
    gemm_mfma<256, 128, false><<<dim3(gbU, 2), 256, 0, stream>>>(
        feat_user, Wt1u, inv + 0 * NP, inv + 4 * NP, 128, t1u, n_user, 256);
    gemm_mfma<128, 128, false><<<dim3(gbI, 1), 256, 0, stream>>>(
        feat_item, Wt1i, inv + 2 * NP, inv + 2 * NP, 1 << 30, t1i, n_item, 128);

    // ---- layer 1 gathers ----
    gather<128, false, true, true><<<gwI, 256, 0, stream>>>(
        t1u, 256, 0, csr0, cursor + 0 * NP, deg + 1 * NP, inv + 1 * NP, b1_rates,
        nullptr, 0, 0, nullptr, nullptr, nullptr, nullptr, nullptr,
        aggI, n_item);
    gather<128, true, true, true><<<gwU, 256, 0, stream>>>(
        t1i, 128, 0, csr1, cursor + 1 * NP, deg + 3 * NP, inv + 3 * NP, b1_rated,
        t1u, 256, 128, csr2, cursor + 2 * NP, deg + 5 * NP, inv + 5 * NP, b1_fol,
        aggU, n_user);

    // t2i (= t1u region, stride 64) Z row: slot held live t1u data until now
    hipMemsetAsync(t2i + (size_t)Z * 64, 0, 128, stream);

    // ---- layer 2 GEMMs ----
    gemm_mfma<128, 128, true><<<dim3(gbU, 1), 256, 0, stream>>>(
        aggU, Wt2u, inv + 0 * NP, inv + 4 * NP, 64, t2u, n_user, 128);
    gemm_mfma<128, 64, true><<<dim3(gbI, 1), 128, 0, stream>>>(
        aggI, Wt2i, inv + 2 * NP, inv + 2 * NP, 1 << 30, t2i, n_item, 64);

    // ---- layer 2 gathers (straight into d_out, fp32) ----
    gather<64, false, false, false><<<gwI, 256, 0, stream>>>(
        t2u, 128, 0, csr0, cursor + 0 * NP, deg + 1 * NP, inv + 1 * NP, b2_rates,
        nullptr, 0, 0, nullptr, nullptr, nullptr, nullptr, nullptr,
        o_item, n_item);
    gather<64, true, false, false><<<gwU, 256, 0, stream>>>(
        t2i, 64, 0, csr1, cursor + 1 * NP, deg + 3 * NP, inv + 3 * NP, b2_rated,
        t2u, 128, 64, csr2, cursor + 2 * NP, deg + 5 * NP, inv + 5 * NP, b2_fol,
        o_user, n_user);
}